// Round 8
// baseline (645.495 us; speedup 1.0000x reference)
//
#include <hip/hip_runtime.h>

// SwitchHeadCore: B=2,S=2048,D=1024,H=8,E=8,P=128,K=2(top-k). T = 4096.

typedef unsigned short u16;
typedef __attribute__((ext_vector_type(8))) short s8v;   // 8 x bf16 (MFMA A/B frag)
typedef __attribute__((ext_vector_type(4))) float f4v;   // MFMA C/D frag
typedef __attribute__((ext_vector_type(4))) unsigned short us4;

#define ATT_SCALE 0.08838834764831845f

__device__ inline u16 bf16_rne(float f) {
  union { float f; unsigned u; } v; v.f = f;
  unsigned r = v.u + 0x7fffu + ((v.u >> 16) & 1u);
  return (u16)(r >> 16);
}
__device__ inline float bf2f(u16 h) {
  union { unsigned u; float f; } v; v.u = ((unsigned)h) << 16;
  return v.f;
}

// async global->LDS, 16B per lane. Global src may be per-lane; LDS dest linear in lane order.
__device__ inline void glds16(const void* g, void* l) {
  __builtin_amdgcn_global_load_lds((const __attribute__((address_space(1))) void*)g,
                                   (__attribute__((address_space(3))) void*)l, 16, 0, 0);
}
// swizzled source column (u16 units) for staging lane index idx (rows of 32 u16, 4 slots of 8)
__device__ inline int swzcol(int idx) {
  int r = idx >> 2;
  return (((idx & 3) ^ ((r + (r >> 2)) & 3)) << 3);
}
#define WAITB() do { asm volatile("s_waitcnt vmcnt(0)" ::: "memory"); __syncthreads(); } while (0)

// ---------------- weight prep ----------------
__global__ void conv_qk(const float* __restrict__ Q, const float* __restrict__ K,
                        u16* __restrict__ Qb, u16* __restrict__ Kb) {
  int i = blockIdx.x * 256 + threadIdx.x;
  const float* src; u16* dst; int off;
  if (i < 262144) { src = Q; dst = Qb; off = i; }
  else            { src = K; dst = Kb; off = i - 262144; }
  float4 v = *(const float4*)&src[(size_t)off * 4];
  us4 o; o[0]=bf16_rne(v.x); o[1]=bf16_rne(v.y); o[2]=bf16_rne(v.z); o[3]=bf16_rne(v.w);
  *(us4*)&dst[(size_t)off * 4] = o;
}

// mode 0: v_w [he][1024 d][128 p] -> vwT [h][p][e][d]
// mode 1: o_w [he][128 p][1024 d] -> owT [d][he*128+p]
__global__ void transpose_w(const float* __restrict__ src, u16* __restrict__ dst, int mode) {
  __shared__ float tile[32][33];
  int he = blockIdx.z;
  int C = mode ? 1024 : 128;
  int r0 = blockIdx.y * 32, c0 = blockIdx.x * 32;
  int lc = threadIdx.x & 31, rr = threadIdx.x >> 5;
  const float* s = src + (size_t)he * 131072;
#pragma unroll
  for (int i = 0; i < 4; ++i) {
    int r = rr + i * 8;
    tile[r][lc] = s[(size_t)(r0 + r) * C + c0 + lc];
  }
  __syncthreads();
#pragma unroll
  for (int i = 0; i < 4; ++i) {
    int c = rr + i * 8;
    float v = tile[lc][c];
    size_t a;
    if (mode) a = (size_t)(c0 + c) * 8192 + (size_t)he * 128 + (r0 + lc);
    else      a = (size_t)(he >> 3) * 1048576 + (size_t)(c0 + c) * 8192 + (size_t)(he & 7) * 1024 + (r0 + lc);
    dst[a] = bf16_rne(v);
  }
}

// ---------------- routing + x->bf16 ----------------
__global__ __launch_bounds__(256, 2) void routing(
    const float* __restrict__ X, const float* __restrict__ SelV, const float* __restrict__ SelO,
    const float* __restrict__ RS, int2* __restrict__ Tvi, float2* __restrict__ Tvg,
    int2* __restrict__ Toi, float2* __restrict__ Tog, u16* __restrict__ Xb) {
  __shared__ float xs[8][1024];
  __shared__ float lgs[8][128];
  int t0 = blockIdx.x * 8;
  int tid = threadIdx.x;
  for (int i = tid; i < 2048; i += 256) {
    int row = i >> 8, c = (i & 255) * 4;
    float4 v = *(const float4*)&X[(size_t)(t0 + row) * 1024 + c];
    *(float4*)&xs[row][c] = v;
    us4 o; o[0]=bf16_rne(v.x); o[1]=bf16_rne(v.y); o[2]=bf16_rne(v.z); o[3]=bf16_rne(v.w);
    *(us4*)&Xb[(size_t)(t0 + row) * 1024 + c] = o;
  }
  __syncthreads();
  {
    int widx = tid & 127, tg = tid >> 7;
    const float* w = (widx < 64) ? (SelV + (size_t)widx * 1024) : (SelO + (size_t)(widx - 64) * 1024);
    float acc[4] = {0.f, 0.f, 0.f, 0.f};
    for (int k = 0; k < 1024; k += 4) {
      float4 wv = *(const float4*)&w[k];
#pragma unroll
      for (int t = 0; t < 4; ++t) {
        float4 xv = *(const float4*)&xs[tg * 4 + t][k];
        acc[t] += wv.x * xv.x + wv.y * xv.y + wv.z * xv.z + wv.w * xv.w;
      }
    }
#pragma unroll
    for (int t = 0; t < 4; ++t) lgs[tg * 4 + t][widx] = acc[t];
  }
  __syncthreads();
  if (tid < 128) {
    float rs = RS[0];
    int tok = tid >> 4, which = (tid >> 3) & 1, h = tid & 7;
    float p[8];
#pragma unroll
    for (int e = 0; e < 8; ++e)
      p[e] = 1.f / (1.f + __expf(-lgs[tok][which * 64 + h * 8 + e]));
    float v1 = -1.f; int i1 = -1;
#pragma unroll
    for (int e = 0; e < 8; ++e) if (p[e] > v1) { v1 = p[e]; i1 = e; }
    float v2 = -1.f; int i2 = -1;
#pragma unroll
    for (int e = 0; e < 8; ++e) if (e != i1 && p[e] > v2) { v2 = p[e]; i2 = e; }
    float ssum = fmaxf(v1 + v2, 1e-9f);
    float g1 = v1 / ssum * rs, g2 = v2 / ssum * rs;
    int t = t0 + tok;
    int lo, hi; float glo, ghi;
    if (i1 < i2) { lo = i1; hi = i2; glo = g1; ghi = g2; }
    else         { lo = i2; hi = i1; glo = g2; ghi = g1; }
    if (which) { Toi[t * 8 + h] = make_int2(lo, hi); Tog[t * 8 + h] = make_float2(glo, ghi); }
    else       { Tvi[t * 8 + h] = make_int2(lo, hi); Tvg[t * 8 + h] = make_float2(glo, ghi); }
  }
}

// ---------------- V bucket build v2: bucket = h*8 + e, role in bit 15 of token ----------------
__global__ void build_buckets2(const int2* __restrict__ Tvi, const float2* __restrict__ Tvg,
                               int* __restrict__ bcnt, u16* __restrict__ btok,
                               float* __restrict__ bgate) {
  int t = blockIdx.x * 256 + threadIdx.x;  // 4096 tokens
#pragma unroll
  for (int h = 0; h < 8; ++h) {
    int2 e = Tvi[t * 8 + h];
    float2 g = Tvg[t * 8 + h];
    int bA = h * 8 + e.x;
    int pA = atomicAdd(&bcnt[bA], 1);
    btok[bA * 4096 + pA] = (u16)t;                 // role 0 -> VpA
    bgate[bA * 4096 + pA] = g.x;
    int bB = h * 8 + e.y;
    int pB = atomicAdd(&bcnt[bB], 1);
    btok[bB * 4096 + pB] = (u16)(t | 0x8000);      // role 1 -> VpB
    bgate[bB * 4096 + pB] = g.y;
  }
}

// ---------------- Q/K projection GEMM: 64x128 tile, dbuf prefetch + swizzle ----------------
// grid (64 tb, 8 nb, 2 qk)
__global__ __launch_bounds__(256) void gemm_qk(
    const u16* __restrict__ Xb, const u16* __restrict__ Wq, const u16* __restrict__ Wk,
    u16* __restrict__ Qo, u16* __restrict__ Ko) {
  __shared__ u16 Ash0[64 * 32], Ash1[64 * 32];
  __shared__ u16 Bsh0[128 * 32], Bsh1[128 * 32];
  const int tb = blockIdx.x, nb = blockIdx.y;
  const u16* W = blockIdx.z ? Wk : Wq;
  u16* Out = blockIdx.z ? Ko : Qo;
  const int tid = threadIdx.x;
  const int wave = tid >> 6, lane = tid & 63;
  const int lg = lane >> 4, lr = lane & 15;
  const int r0 = tid >> 2, r1 = (tid + 256) >> 2;
  const int c0 = swzcol(tid), c1 = swzcol(tid + 256);
  const size_t aw  = (size_t)(tb * 64 + r0) * 1024 + c0;
  const size_t bw0 = (size_t)(nb * 128 + r0) * 1024 + c0;
  const size_t bw1 = (size_t)(nb * 128 + r1) * 1024 + c1;
  const int csl = (lg ^ ((lr + (lr >> 2)) & 3)) << 3;
  f4v acc[4][2] = {};
#define STG_QK(A, B, k0) do { \
    glds16(&Xb[aw + (k0)], &A[tid * 8]); \
    glds16(&W[bw0 + (k0)], &B[tid * 8]); \
    glds16(&W[bw1 + (k0)], &B[(tid + 256) * 8]); \
  } while (0)
#define CMP_QK(A, B) do { \
    s8v af[4], bfr[2]; \
    _Pragma("unroll") for (int m = 0; m < 4; ++m) af[m] = *(const s8v*)&A[(m * 16 + lr) * 32 + csl]; \
    _Pragma("unroll") for (int n = 0; n < 2; ++n) bfr[n] = *(const s8v*)&B[(wave * 32 + n * 16 + lr) * 32 + csl]; \
    _Pragma("unroll") for (int m = 0; m < 4; ++m) \
      _Pragma("unroll") for (int n = 0; n < 2; ++n) \
        acc[m][n] = __builtin_amdgcn_mfma_f32_16x16x32_bf16(af[m], bfr[n], acc[m][n], 0, 0, 0); \
  } while (0)
  STG_QK(Ash0, Bsh0, 0);
  for (int kt = 0; kt < 32; kt += 2) {
    WAITB();
    if (kt + 1 < 32) STG_QK(Ash1, Bsh1, (kt + 1) * 32);
    CMP_QK(Ash0, Bsh0);
    WAITB();
    if (kt + 2 < 32) STG_QK(Ash0, Bsh0, (kt + 2) * 32);
    CMP_QK(Ash1, Bsh1);
  }
#undef STG_QK
#undef CMP_QK
#pragma unroll
  for (int m = 0; m < 4; ++m) {
    int tbase = tb * 64 + m * 16 + lg * 4;
    int b = tbase >> 11, s = tbase & 2047;
#pragma unroll
    for (int n = 0; n < 2; ++n) {
      int p = wave * 32 + n * 16 + lr;
      size_t base = ((size_t)(b * 8 + nb) * 2048 + s) * 128 + p;
#pragma unroll
      for (int j = 0; j < 4; ++j)
        Out[base + (size_t)j * 128] = bf16_rne(acc[m][n][j]);
    }
  }
}

// ---------------- V expert GEMM v3: per-(h,e) buckets, 128x128 tile, role-split partials ----------------
// grid (32 tiles, 64 buckets). VpA/VpB [t][h*128+p] bf16, each (t,h) written exactly once per buffer.
__global__ __launch_bounds__(256) void gemm_v_e(
    const u16* __restrict__ Xb, const u16* __restrict__ Vw /*[h][p][e][d]*/,
    const int* __restrict__ bcnt, const u16* __restrict__ btok,
    const float* __restrict__ bgate, u16* __restrict__ VpA, u16* __restrict__ VpB) {
  const int bucket = blockIdx.y;
  const int h = bucket >> 3, e = bucket & 7;
  const int cnt = bcnt[bucket];
  const int tile = blockIdx.x;
  if (tile * 128 >= cnt) return;
  __shared__ u16 Ash0[128 * 32], Ash1[128 * 32];
  __shared__ u16 Bsh0[128 * 32], Bsh1[128 * 32];
  __shared__ int toksh[128];
  __shared__ float gsh[128];
  const int tid = threadIdx.x;
  if (tid < 128) {
    int ar = tile * 128 + tid;
    if (ar < cnt) {
      toksh[tid] = btok[bucket * 4096 + ar];
      gsh[tid] = bgate[bucket * 4096 + ar];
    } else { toksh[tid] = 0; gsh[tid] = 0.f; }
  }
  __syncthreads();
  const int wave = tid >> 6, lane = tid & 63;
  const int wm = wave >> 1, wn = wave & 1;
  const int lg = lane >> 4, lr = lane & 15;
  const int r0 = tid >> 2, r1 = (tid + 256) >> 2;
  const int c0 = swzcol(tid), c1 = swzcol(tid + 256);
  const size_t aw0 = (size_t)(toksh[r0] & 0xFFF) * 1024 + c0;
  const size_t aw1 = (size_t)(toksh[r1] & 0xFFF) * 1024 + c1;
  const size_t bw0 = ((size_t)(h * 128 + r0) * 8 + e) * 1024 + c0;
  const size_t bw1 = ((size_t)(h * 128 + r1) * 8 + e) * 1024 + c1;
  const int csl = (lg ^ ((lr + (lr >> 2)) & 3)) << 3;
  f4v acc[4][4] = {};
#define STG_VE(A, B, k0) do { \
    glds16(&Xb[aw0 + (k0)], &A[tid * 8]); \
    glds16(&Xb[aw1 + (k0)], &A[(tid + 256) * 8]); \
    glds16(&Vw[bw0 + (k0)], &B[tid * 8]); \
    glds16(&Vw[bw1 + (k0)], &B[(tid + 256) * 8]); \
  } while (0)
#define CMP_VE(A, B) do { \
    s8v af[4], bfr[4]; \
    _Pragma("unroll") for (int m = 0; m < 4; ++m) af[m] = *(const s8v*)&A[(wm * 64 + m * 16 + lr) * 32 + csl]; \
    _Pragma("unroll") for (int n = 0; n < 4; ++n) bfr[n] = *(const s8v*)&B[(wn * 64 + n * 16 + lr) * 32 + csl]; \
    _Pragma("unroll") for (int m = 0; m < 4; ++m) \
      _Pragma("unroll") for (int n = 0; n < 4; ++n) \
        acc[m][n] = __builtin_amdgcn_mfma_f32_16x16x32_bf16(af[m], bfr[n], acc[m][n], 0, 0, 0); \
  } while (0)
  STG_VE(Ash0, Bsh0, 0);
  for (int kt = 0; kt < 32; kt += 2) {
    WAITB();
    if (kt + 1 < 32) STG_VE(Ash1, Bsh1, (kt + 1) * 32);
    CMP_VE(Ash0, Bsh0);
    WAITB();
    if (kt + 2 < 32) STG_VE(Ash0, Bsh0, (kt + 2) * 32);
    CMP_VE(Ash1, Bsh1);
  }
#undef STG_VE
#undef CMP_VE
#pragma unroll
  for (int m = 0; m < 4; ++m) {
#pragma unroll
    for (int j = 0; j < 4; ++j) {
      int row = wm * 64 + m * 16 + lg * 4 + j;
      int ar = tile * 128 + row;
      if (ar < cnt) {
        int entry = toksh[row];
        int tok = entry & 0xFFF;
        u16* dst = (entry & 0x8000) ? VpB : VpA;
        float g = gsh[row];
#pragma unroll
        for (int n = 0; n < 4; ++n) {
          int p = wn * 64 + n * 16 + lr;
          dst[(size_t)tok * 1024 + h * 128 + p] = bf16_rne(g * acc[m][n][j]);
        }
      }
    }
  }
}

// ---------------- vadd_transpose: VT[bh][p][s] = VpA[t][hp] + VpB[t][hp] ----------------
__global__ void vadd_transpose(const u16* __restrict__ VpA, const u16* __restrict__ VpB,
                               u16* __restrict__ VT) {
  __shared__ u16 tile[64][136];
  const int sb = blockIdx.x, bh = blockIdx.y;
  const int b = bh >> 3, h = bh & 7;
  const int tid = threadIdx.x;
#pragma unroll
  for (int it = 0; it < 4; ++it) {
    int idx = tid + it * 256;
    int r = idx >> 4, c8 = (idx & 15) << 3;
    size_t off = (size_t)(b * 2048 + sb * 64 + r) * 1024 + h * 128 + c8;
    s8v va = *(const s8v*)&VpA[off];
    s8v vb = *(const s8v*)&VpB[off];
    s8v o;
#pragma unroll
    for (int j = 0; j < 8; ++j) o[j] = (short)bf16_rne(bf2f((u16)va[j]) + bf2f((u16)vb[j]));
    *(s8v*)&tile[r][c8] = o;
  }
  __syncthreads();
#pragma unroll
  for (int it = 0; it < 8; ++it) {
    int idx = tid + it * 256;
    int p = idx >> 4, c4 = (idx & 15) << 2;
    us4 o;
#pragma unroll
    for (int j = 0; j < 4; ++j) o[j] = tile[c4 + j][p];
    *(us4*)&VT[((size_t)bh * 128 + p) * 2048 + sb * 64 + c4] = o;
  }
}

// ---------------- attention (flash-style) ----------------
__global__ __launch_bounds__(256, 2) void attn(
    const u16* __restrict__ Q, const u16* __restrict__ K,
    const u16* __restrict__ VT, u16* __restrict__ CTX) {
  __shared__ u16 Kt[64 * 136];
  __shared__ u16 Vt[128 * 72];
  __shared__ u16 Pl[4][16 * 72];
  const int qb = blockIdx.x, bh = blockIdx.y;
  const int tid = threadIdx.x;
  const int wave = tid >> 6, lane = tid & 63;
  const int lg = lane >> 4, lr = lane & 15;
  const size_t base = (size_t)bh * 2048 * 128;
  const int q0 = qb * 64 + wave * 16;
  s8v qf[4];
#pragma unroll
  for (int ks = 0; ks < 4; ++ks)
    qf[ks] = *(const s8v*)&Q[base + (size_t)(q0 + lr) * 128 + ks * 32 + lg * 8];
  f4v cacc[8] = {};
  float mrun = -1e30f, ssum = 0.f;
  for (int kb = 0; kb < 32; ++kb) {
    __syncthreads();
#pragma unroll
    for (int i = 0; i < 4; ++i) {
      int idx = tid + i * 256;
      int r = idx >> 4, c8 = (idx & 15) << 3;
      *(s8v*)&Kt[r * 136 + c8] = *(const s8v*)&K[base + (size_t)(kb * 64 + r) * 128 + c8];
    }
#pragma unroll
    for (int i = 0; i < 4; ++i) {
      int idx = tid + i * 256;
      int r = idx >> 3, c8 = (idx & 7) << 3;
      *(s8v*)&Vt[r * 72 + c8] = *(const s8v*)&VT[base + (size_t)r * 2048 + kb * 64 + c8];
    }
    __syncthreads();
    f4v sc[4] = {};
#pragma unroll
    for (int ks = 0; ks < 4; ++ks) {
#pragma unroll
      for (int m = 0; m < 4; ++m) {
        s8v ak = *(const s8v*)&Kt[(m * 16 + lr) * 136 + ks * 32 + lg * 8];
        sc[m] = __builtin_amdgcn_mfma_f32_16x16x32_bf16(ak, qf[ks], sc[m], 0, 0, 0);
      }
    }
    float tmax = -1e30f;
#pragma unroll
    for (int m = 0; m < 4; ++m)
#pragma unroll
      for (int j = 0; j < 4; ++j) {
        float v = sc[m][j] * ATT_SCALE;
        sc[m][j] = v;
        tmax = fmaxf(tmax, v);
      }
    tmax = fmaxf(tmax, __shfl_xor(tmax, 16));
    tmax = fmaxf(tmax, __shfl_xor(tmax, 32));
    float mnew = fmaxf(mrun, tmax);
    float f = __expf(mrun - mnew);
    mrun = mnew;
    float psum = 0.f;
#pragma unroll
    for (int m = 0; m < 4; ++m) {
      us4 pk;
#pragma unroll
      for (int j = 0; j < 4; ++j) {
        float pe = __expf(sc[m][j] - mnew);
        psum += pe;
        pk[j] = bf16_rne(pe);
      }
      *(us4*)&Pl[wave][lr * 72 + m * 16 + lg * 4] = pk;
    }
    psum += __shfl_xor(psum, 16);
    psum += __shfl_xor(psum, 32);
    ssum = ssum * f + psum;
#pragma unroll
    for (int mr = 0; mr < 8; ++mr)
#pragma unroll
      for (int j = 0; j < 4; ++j) cacc[mr][j] *= f;
#pragma unroll
    for (int ks = 0; ks < 2; ++ks) {
      s8v bp = *(const s8v*)&Pl[wave][lr * 72 + ks * 32 + lg * 8];
#pragma unroll
      for (int mr = 0; mr < 8; ++mr) {
        s8v av = *(const s8v*)&Vt[(mr * 16 + lr) * 72 + ks * 32 + lg * 8];
        cacc[mr] = __builtin_amdgcn_mfma_f32_16x16x32_bf16(av, bp, cacc[mr], 0, 0, 0);
      }
    }
  }
  float rinv = 1.f / ssum;
#pragma unroll
  for (int mr = 0; mr < 8; ++mr) {
    us4 pk;
#pragma unroll
    for (int j = 0; j < 4; ++j) pk[j] = bf16_rne(cacc[mr][j] * rinv);
    *(us4*)&CTX[base + (size_t)(q0 + lr) * 128 + mr * 16 + lg * 4] = pk;
  }
}

// ---------------- pregate: CTXG[t][he*128+p] = gate_o[t,he] * ctx[t,h,p] ----------------
__global__ __launch_bounds__(256) void pregate(
    const u16* __restrict__ CTX, const int2* __restrict__ Toi, const float2* __restrict__ Tog,
    u16* __restrict__ CTXG) {
  const int t = blockIdx.x;
  const int tid = threadIdx.x;
  __shared__ float gsh[64];
  if (tid < 64) {
    int h = tid >> 3, e = tid & 7;
    int2 ei = Toi[t * 8 + h];
    float2 gg = Tog[t * 8 + h];
    gsh[tid] = (e == ei.x) ? gg.x : ((e == ei.y) ? gg.y : 0.f);
  }
  __syncthreads();
  const int b = t >> 11, s = t & 2047;
#pragma unroll
  for (int c = 0; c < 4; ++c) {
    int chunk = tid + c * 256;            // 0..1023 chunks of 8 elems
    int he = chunk >> 4, p8 = (chunk & 15) << 3;
    int h = he >> 3;
    float g = gsh[he];
    s8v o;
    if (g != 0.f) {
      s8v v = *(const s8v*)&CTX[((size_t)(b * 8 + h) * 2048 + s) * 128 + p8];
#pragma unroll
      for (int j = 0; j < 8; ++j) o[j] = (short)bf16_rne(bf2f((u16)v[j]) * g);
    } else {
#pragma unroll
      for (int j = 0; j < 8; ++j) o[j] = 0;
    }
    *(s8v*)&CTXG[(size_t)t * 8192 + chunk * 8] = o;
  }
}

// ---------------- O projection: dense 128^2, dbuf prefetch + swizzle, split-K=2 ----------------
// grid (32 tb, 8 db, 2 kz). kz=0 -> OUT fp32 direct; kz=1 -> partials (2 x 8MB halves).
__global__ __launch_bounds__(256) void gemm_o_dense(
    const u16* __restrict__ CTXG, const u16* __restrict__ Ow /*[d][8192]*/,
    float* __restrict__ OUT, float* __restrict__ OP1a, float* __restrict__ OP1b) {
  __shared__ u16 Ash0[128 * 32], Ash1[128 * 32];
  __shared__ u16 Bsh0[128 * 32], Bsh1[128 * 32];
  const int tb = blockIdx.x, db = blockIdx.y, kz = blockIdx.z;
  const int tid = threadIdx.x;
  const int wave = tid >> 6, lane = tid & 63;
  const int wm = wave >> 1, wn = wave & 1;
  const int lg = lane >> 4, lr = lane & 15;
  const size_t kbase = (size_t)kz * 4096;
  const int r0 = tid >> 2, r1 = (tid + 256) >> 2;
  const int c0 = swzcol(tid), c1 = swzcol(tid + 256);
  const size_t aw0 = (size_t)(tb * 128 + r0) * 8192 + kbase + c0;
  const size_t aw1 = (size_t)(tb * 128 + r1) * 8192 + kbase + c1;
  const size_t bw0 = (size_t)(db * 128 + r0) * 8192 + kbase + c0;
  const size_t bw1 = (size_t)(db * 128 + r1) * 8192 + kbase + c1;
  const int csl = (lg ^ ((lr + (lr >> 2)) & 3)) << 3;
  f4v acc[4][4] = {};
#define STG_O(A, B, k0) do { \
    glds16(&CTXG[aw0 + (k0)], &A[tid * 8]); \
    glds16(&CTXG[aw1 + (k0)], &A[(tid + 256) * 8]); \
    glds16(&Ow[bw0 + (k0)], &B[tid * 8]); \
    glds16(&Ow[bw1 + (k0)], &B[(tid + 256) * 8]); \
  } while (0)
#define CMP_O(A, B) do { \
    s8v af[4], bfr[4]; \
    _Pragma("unroll") for (int m = 0; m < 4; ++m) af[m] = *(const s8v*)&A[(wm * 64 + m * 16 + lr) * 32 + csl]; \
    _Pragma("unroll") for (int n = 0; n < 4; ++n) bfr[n] = *(const s8v*)&B[(wn * 64 + n * 16 + lr) * 32 + csl]; \
    _Pragma("unroll") for (int m = 0; m < 4; ++m) \
      _Pragma("unroll") for (int n = 0; n < 4; ++n) \
        acc[m][n] = __builtin_amdgcn_mfma_f32_16x16x32_bf16(af[m], bfr[n], acc[m][n], 0, 0, 0); \
  } while (0)
  STG_O(Ash0, Bsh0, 0);
  for (int kt = 0; kt < 128; kt += 2) {
    WAITB();
    if (kt + 1 < 128) STG_O(Ash1, Bsh1, (kt + 1) * 32);
    CMP_O(Ash0, Bsh0);
    WAITB();
    if (kt + 2 < 128) STG_O(Ash0, Bsh0, (kt + 2) * 32);
    CMP_O(Ash1, Bsh1);
  }
#undef STG_O
#undef CMP_O
  float* OP;
  if (kz == 0) OP = OUT;
  else OP = (tb < 16) ? OP1a : OP1b;
  const int toff = (kz == 0) ? tb * 128 : (tb & 15) * 128;
#pragma unroll
  for (int m = 0; m < 4; ++m) {
    int t = toff + wm * 64 + m * 16 + lg * 4;
#pragma unroll
    for (int n = 0; n < 4; ++n) {
      int d = db * 128 + wn * 64 + n * 16 + lr;
#pragma unroll
      for (int j = 0; j < 4; ++j)
        OP[(size_t)(t + j) * 1024 + d] = acc[m][n][j];
    }
  }
}

// ---------------- OUT += partial (split halves) ----------------
__global__ void add_inplace(float* __restrict__ OUT, const float* __restrict__ P0,
                            const float* __restrict__ P1) {
  size_t i = ((size_t)blockIdx.x * 256 + threadIdx.x) * 4;  // 4M floats
  const float* P = (i < 2097152) ? (P0 + i) : (P1 + (i - 2097152));
  float4 a = *(const float4*)&OUT[i];
  float4 b = *(const float4*)P;
  *(float4*)&OUT[i] = make_float4(a.x + b.x, a.y + b.y, a.z + b.z, a.w + b.w);
}

extern "C" void kernel_launch(void* const* d_in, const int* in_sizes, int n_in,
                              void* d_out, int out_size, void* d_ws, size_t ws_size,
                              hipStream_t stream) {
  const float* x     = (const float*)d_in[0];
  const float* q_w   = (const float*)d_in[1];
  const float* k_w   = (const float*)d_in[2];
  const float* v_w   = (const float*)d_in[3];
  const float* o_w   = (const float*)d_in[4];
  const float* sel_v = (const float*)d_in[5];
  const float* sel_o = (const float*)d_in[6];
  const float* rs    = (const float*)d_in[7];

  char* ws = (char*)d_ws;
  const size_t MB = 1048576;
  const size_t KB = 1024;
  // Timeline / overlays (96 MB peak, proven ws >= 97.5 MB):
  u16*    xb    = (u16*)(ws);                        // [0,8M): xb -> ctx -> op1a
  u16*    ctx   = (u16*)(ws);
  float*  op1a  = (float*)(ws);
  u16*    qwb   = (u16*)(ws + 8 * MB);               // [8,10M) dead after gemm_qk
  u16*    kwb   = (u16*)(ws + 10 * MB);              // [10,12M)
  u16*    ctxg  = (u16*)(ws + 8 * MB);               // [8,72M) from pregate on
  u16*    vwT   = (u16*)(ws + 12 * MB);              // [12,28M) dead after gemm_v_e
  u16*    vt    = (u16*)(ws + 12 * MB);              // [12,20M) written after vwT dead
  u16*    vpA   = (u16*)(ws + 28 * MB);              // [28,36M) role-0 partials
  u16*    vpB   = (u16*)(ws + 36 * MB);              // [36,44M) role-1 partials
  u16*    qh    = (u16*)(ws + 49 * MB + 512 * KB);   // [49.5,57.5M)
  u16*    kh    = (u16*)(ws + 57 * MB + 512 * KB);   // [57.5,65.5M)
  int2*   tvi   = (int2*)(ws + 72 * MB);             // [72,80M): routing/bucket meta -> op1b
  float2* tvg   = (float2*)(ws + 72 * MB + 256 * KB);
  int2*   toi   = (int2*)(ws + 72 * MB + 512 * KB);
  float2* tog   = (float2*)(ws + 72 * MB + 768 * KB);
  int*    bcnt2 = (int*)(ws + 73 * MB);              // 256B (pad to 4K)
  u16*    btok2 = (u16*)(ws + 73 * MB + 4 * KB);     // 512K
  float*  bgate2= (float*)(ws + 73 * MB + 520 * KB); // 1M -> ends 73M+1544K
  float*  op1b  = (float*)(ws + 72 * MB);
  u16*    owT   = (u16*)(ws + 80 * MB);              // [80,96M) live until gemm_o_dense
  float*  outp  = (float*)d_out;

  hipLaunchKernelGGL(conv_qk, dim3(2048), dim3(256), 0, stream, q_w, k_w, qwb, kwb);
  hipLaunchKernelGGL(transpose_w, dim3(4, 32, 64), dim3(256), 0, stream, v_w, vwT, 0);
  hipLaunchKernelGGL(transpose_w, dim3(32, 4, 64), dim3(256), 0, stream, o_w, owT, 1);
  hipMemsetAsync(bcnt2, 0, 4 * KB, stream);
  hipLaunchKernelGGL(routing, dim3(512), dim3(256), 0, stream, x, sel_v, sel_o, rs, tvi, tvg, toi, tog, xb);
  hipLaunchKernelGGL(build_buckets2, dim3(16), dim3(256), 0, stream, tvi, tvg, bcnt2, btok2, bgate2);
  hipLaunchKernelGGL(gemm_v_e, dim3(32, 64), dim3(256), 0, stream, xb, vwT, bcnt2, btok2, bgate2, vpA, vpB);
  hipLaunchKernelGGL(vadd_transpose, dim3(32, 16), dim3(256), 0, stream, vpA, vpB, vt);
  hipLaunchKernelGGL(gemm_qk, dim3(64, 8, 2), dim3(256), 0, stream, xb, qwb, kwb, qh, kh);
  hipLaunchKernelGGL(attn, dim3(32, 16), dim3(256), 0, stream, qh, kh, vt, ctx);
  hipLaunchKernelGGL(pregate, dim3(4096), dim3(256), 0, stream, ctx, toi, tog, ctxg);
  hipLaunchKernelGGL(gemm_o_dense, dim3(32, 8, 2), dim3(256), 0, stream, ctxg, owT, outp, op1a, op1b);
  hipLaunchKernelGGL(add_inplace, dim3(4096), dim3(256), 0, stream, outp, op1a, op1b);
}

// Round 9
// 422.417 us; speedup vs baseline: 1.5281x; 1.5281x over previous
//
#include <hip/hip_runtime.h>

// SwitchHeadCore: B=2,S=2048,D=1024,H=8,E=8,P=128,K=2(top-k). T = 4096.

typedef unsigned short u16;
typedef __attribute__((ext_vector_type(8))) short s8v;   // 8 x bf16 (MFMA A/B frag)
typedef __attribute__((ext_vector_type(4))) float f4v;   // MFMA C/D frag
typedef __attribute__((ext_vector_type(4))) unsigned short us4;

#define ATT_SCALE 0.08838834764831845f

__device__ inline u16 bf16_rne(float f) {
  union { float f; unsigned u; } v; v.f = f;
  unsigned r = v.u + 0x7fffu + ((v.u >> 16) & 1u);
  return (u16)(r >> 16);
}
__device__ inline float bf2f(u16 h) {
  union { unsigned u; float f; } v; v.u = ((unsigned)h) << 16;
  return v.f;
}

// async global->LDS, 16B per lane. Global src may be per-lane; LDS dest linear in lane order.
__device__ inline void glds16(const void* g, void* l) {
  __builtin_amdgcn_global_load_lds((const __attribute__((address_space(1))) void*)g,
                                   (__attribute__((address_space(3))) void*)l, 16, 0, 0);
}
// swizzled source column (u16 units) for staging lane index idx (rows of 32 u16, 4 slots of 8)
__device__ inline int swzcol(int idx) {
  int r = idx >> 2;
  return (((idx & 3) ^ ((r + (r >> 2)) & 3)) << 3);
}
#define WAITB() do { asm volatile("s_waitcnt vmcnt(0)" ::: "memory"); __syncthreads(); } while (0)

// ---------------- weight prep ----------------
__global__ void conv_qk(const float* __restrict__ Q, const float* __restrict__ K,
                        u16* __restrict__ Qb, u16* __restrict__ Kb) {
  int i = blockIdx.x * 256 + threadIdx.x;
  const float* src; u16* dst; int off;
  if (i < 262144) { src = Q; dst = Qb; off = i; }
  else            { src = K; dst = Kb; off = i - 262144; }
  float4 v = *(const float4*)&src[(size_t)off * 4];
  us4 o; o[0]=bf16_rne(v.x); o[1]=bf16_rne(v.y); o[2]=bf16_rne(v.z); o[3]=bf16_rne(v.w);
  *(us4*)&dst[(size_t)off * 4] = o;
}

// mode 0: v_w [he][1024 d][128 p] -> vwT [h][p][e][d]
// mode 1: o_w [he][128 p][1024 d] -> owT [d][he*128+p]
__global__ void transpose_w(const float* __restrict__ src, u16* __restrict__ dst, int mode) {
  __shared__ float tile[32][33];
  int he = blockIdx.z;
  int C = mode ? 1024 : 128;
  int r0 = blockIdx.y * 32, c0 = blockIdx.x * 32;
  int lc = threadIdx.x & 31, rr = threadIdx.x >> 5;
  const float* s = src + (size_t)he * 131072;
#pragma unroll
  for (int i = 0; i < 4; ++i) {
    int r = rr + i * 8;
    tile[r][lc] = s[(size_t)(r0 + r) * C + c0 + lc];
  }
  __syncthreads();
#pragma unroll
  for (int i = 0; i < 4; ++i) {
    int c = rr + i * 8;
    float v = tile[lc][c];
    size_t a;
    if (mode) a = (size_t)(c0 + c) * 8192 + (size_t)he * 128 + (r0 + lc);
    else      a = (size_t)(he >> 3) * 1048576 + (size_t)(c0 + c) * 8192 + (size_t)(he & 7) * 1024 + (r0 + lc);
    dst[a] = bf16_rne(v);
  }
}

// ---------------- routing + x->bf16 ----------------
__global__ __launch_bounds__(256, 2) void routing(
    const float* __restrict__ X, const float* __restrict__ SelV, const float* __restrict__ SelO,
    const float* __restrict__ RS, int2* __restrict__ Tvi, float2* __restrict__ Tvg,
    int2* __restrict__ Toi, float2* __restrict__ Tog, u16* __restrict__ Xb) {
  __shared__ float xs[8][1024];
  __shared__ float lgs[8][128];
  int t0 = blockIdx.x * 8;
  int tid = threadIdx.x;
  for (int i = tid; i < 2048; i += 256) {
    int row = i >> 8, c = (i & 255) * 4;
    float4 v = *(const float4*)&X[(size_t)(t0 + row) * 1024 + c];
    *(float4*)&xs[row][c] = v;
    us4 o; o[0]=bf16_rne(v.x); o[1]=bf16_rne(v.y); o[2]=bf16_rne(v.z); o[3]=bf16_rne(v.w);
    *(us4*)&Xb[(size_t)(t0 + row) * 1024 + c] = o;
  }
  __syncthreads();
  {
    int widx = tid & 127, tg = tid >> 7;
    const float* w = (widx < 64) ? (SelV + (size_t)widx * 1024) : (SelO + (size_t)(widx - 64) * 1024);
    float acc[4] = {0.f, 0.f, 0.f, 0.f};
    for (int k = 0; k < 1024; k += 4) {
      float4 wv = *(const float4*)&w[k];
#pragma unroll
      for (int t = 0; t < 4; ++t) {
        float4 xv = *(const float4*)&xs[tg * 4 + t][k];
        acc[t] += wv.x * xv.x + wv.y * xv.y + wv.z * xv.z + wv.w * xv.w;
      }
    }
#pragma unroll
    for (int t = 0; t < 4; ++t) lgs[tg * 4 + t][widx] = acc[t];
  }
  __syncthreads();
  if (tid < 128) {
    float rs = RS[0];
    int tok = tid >> 4, which = (tid >> 3) & 1, h = tid & 7;
    float p[8];
#pragma unroll
    for (int e = 0; e < 8; ++e)
      p[e] = 1.f / (1.f + __expf(-lgs[tok][which * 64 + h * 8 + e]));
    float v1 = -1.f; int i1 = -1;
#pragma unroll
    for (int e = 0; e < 8; ++e) if (p[e] > v1) { v1 = p[e]; i1 = e; }
    float v2 = -1.f; int i2 = -1;
#pragma unroll
    for (int e = 0; e < 8; ++e) if (e != i1 && p[e] > v2) { v2 = p[e]; i2 = e; }
    float ssum = fmaxf(v1 + v2, 1e-9f);
    float g1 = v1 / ssum * rs, g2 = v2 / ssum * rs;
    int t = t0 + tok;
    int lo, hi; float glo, ghi;
    if (i1 < i2) { lo = i1; hi = i2; glo = g1; ghi = g2; }
    else         { lo = i2; hi = i1; glo = g2; ghi = g1; }
    if (which) { Toi[t * 8 + h] = make_int2(lo, hi); Tog[t * 8 + h] = make_float2(glo, ghi); }
    else       { Tvi[t * 8 + h] = make_int2(lo, hi); Tvg[t * 8 + h] = make_float2(glo, ghi); }
  }
}

// ---------------- V bucket build v3: wave-aggregated, LDS counters, 1 block/head ----------------
// bucket = h*8 + e; role in bit 15 of token entry. Zero global atomics.
__global__ __launch_bounds__(256) void build_buckets2(
    const int2* __restrict__ Tvi, const float2* __restrict__ Tvg,
    int* __restrict__ bcnt, u16* __restrict__ btok, float* __restrict__ bgate) {
  const int h = blockIdx.x;
  const int tid = threadIdx.x;
  const int lane = tid & 63;
  __shared__ int cnt[8];
  if (tid < 8) cnt[tid] = 0;
  __syncthreads();
  for (int chunk = 0; chunk < 16; ++chunk) {
    int t = chunk * 256 + tid;
    int2 e = Tvi[t * 8 + h];
    float2 g = Tvg[t * 8 + h];
#pragma unroll
    for (int role = 0; role < 2; ++role) {
      int mye = role ? e.y : e.x;
      float myg = role ? g.y : g.x;
      u16 entry = role ? (u16)(t | 0x8000) : (u16)t;
#pragma unroll
      for (int ee = 0; ee < 8; ++ee) {
        unsigned long long mask = __ballot(mye == ee);
        if (mye == ee) {
          int prefix = __popcll(mask & ((1ull << lane) - 1ull));
          int leader = __ffsll((unsigned long long)mask) - 1;
          int base = 0;
          if (lane == leader) base = atomicAdd(&cnt[ee], (int)__popcll(mask));
          base = __shfl(base, leader);
          int pos = base + prefix;
          btok[(h * 8 + ee) * 4096 + pos] = entry;
          bgate[(h * 8 + ee) * 4096 + pos] = myg;
        }
      }
    }
  }
  __syncthreads();
  if (tid < 8) bcnt[h * 8 + tid] = cnt[tid];
}

// ---------------- Q/K projection GEMM: 64x128 tile, dbuf prefetch + swizzle ----------------
// grid (64 tb, 8 nb, 2 qk)
__global__ __launch_bounds__(256) void gemm_qk(
    const u16* __restrict__ Xb, const u16* __restrict__ Wq, const u16* __restrict__ Wk,
    u16* __restrict__ Qo, u16* __restrict__ Ko) {
  __shared__ u16 Ash0[64 * 32], Ash1[64 * 32];
  __shared__ u16 Bsh0[128 * 32], Bsh1[128 * 32];
  const int tb = blockIdx.x, nb = blockIdx.y;
  const u16* W = blockIdx.z ? Wk : Wq;
  u16* Out = blockIdx.z ? Ko : Qo;
  const int tid = threadIdx.x;
  const int wave = tid >> 6, lane = tid & 63;
  const int lg = lane >> 4, lr = lane & 15;
  const int r0 = tid >> 2, r1 = (tid + 256) >> 2;
  const int c0 = swzcol(tid), c1 = swzcol(tid + 256);
  const size_t aw  = (size_t)(tb * 64 + r0) * 1024 + c0;
  const size_t bw0 = (size_t)(nb * 128 + r0) * 1024 + c0;
  const size_t bw1 = (size_t)(nb * 128 + r1) * 1024 + c1;
  const int csl = (lg ^ ((lr + (lr >> 2)) & 3)) << 3;
  f4v acc[4][2] = {};
#define STG_QK(A, B, k0) do { \
    glds16(&Xb[aw + (k0)], &A[tid * 8]); \
    glds16(&W[bw0 + (k0)], &B[tid * 8]); \
    glds16(&W[bw1 + (k0)], &B[(tid + 256) * 8]); \
  } while (0)
#define CMP_QK(A, B) do { \
    s8v af[4], bfr[2]; \
    _Pragma("unroll") for (int m = 0; m < 4; ++m) af[m] = *(const s8v*)&A[(m * 16 + lr) * 32 + csl]; \
    _Pragma("unroll") for (int n = 0; n < 2; ++n) bfr[n] = *(const s8v*)&B[(wave * 32 + n * 16 + lr) * 32 + csl]; \
    _Pragma("unroll") for (int m = 0; m < 4; ++m) \
      _Pragma("unroll") for (int n = 0; n < 2; ++n) \
        acc[m][n] = __builtin_amdgcn_mfma_f32_16x16x32_bf16(af[m], bfr[n], acc[m][n], 0, 0, 0); \
  } while (0)
  STG_QK(Ash0, Bsh0, 0);
  for (int kt = 0; kt < 32; kt += 2) {
    WAITB();
    if (kt + 1 < 32) STG_QK(Ash1, Bsh1, (kt + 1) * 32);
    CMP_QK(Ash0, Bsh0);
    WAITB();
    if (kt + 2 < 32) STG_QK(Ash0, Bsh0, (kt + 2) * 32);
    CMP_QK(Ash1, Bsh1);
  }
#undef STG_QK
#undef CMP_QK
#pragma unroll
  for (int m = 0; m < 4; ++m) {
    int tbase = tb * 64 + m * 16 + lg * 4;
    int b = tbase >> 11, s = tbase & 2047;
#pragma unroll
    for (int n = 0; n < 2; ++n) {
      int p = wave * 32 + n * 16 + lr;
      size_t base = ((size_t)(b * 8 + nb) * 2048 + s) * 128 + p;
#pragma unroll
      for (int j = 0; j < 4; ++j)
        Out[base + (size_t)j * 128] = bf16_rne(acc[m][n][j]);
    }
  }
}

// ---------------- V expert GEMM v3: per-(h,e) buckets, 128x128 tile, role-split partials ----------------
// grid (32 tiles, 64 buckets). VpA/VpB [t][h*128+p] bf16, each (t,h) written exactly once per buffer.
__global__ __launch_bounds__(256) void gemm_v_e(
    const u16* __restrict__ Xb, const u16* __restrict__ Vw /*[h][p][e][d]*/,
    const int* __restrict__ bcnt, const u16* __restrict__ btok,
    const float* __restrict__ bgate, u16* __restrict__ VpA, u16* __restrict__ VpB) {
  const int bucket = blockIdx.y;
  const int h = bucket >> 3, e = bucket & 7;
  const int cnt = bcnt[bucket];
  const int tile = blockIdx.x;
  if (tile * 128 >= cnt) return;
  __shared__ u16 Ash0[128 * 32], Ash1[128 * 32];
  __shared__ u16 Bsh0[128 * 32], Bsh1[128 * 32];
  __shared__ int toksh[128];
  __shared__ float gsh[128];
  const int tid = threadIdx.x;
  if (tid < 128) {
    int ar = tile * 128 + tid;
    if (ar < cnt) {
      toksh[tid] = btok[bucket * 4096 + ar];
      gsh[tid] = bgate[bucket * 4096 + ar];
    } else { toksh[tid] = 0; gsh[tid] = 0.f; }
  }
  __syncthreads();
  const int wave = tid >> 6, lane = tid & 63;
  const int wm = wave >> 1, wn = wave & 1;
  const int lg = lane >> 4, lr = lane & 15;
  const int r0 = tid >> 2, r1 = (tid + 256) >> 2;
  const int c0 = swzcol(tid), c1 = swzcol(tid + 256);
  const size_t aw0 = (size_t)(toksh[r0] & 0xFFF) * 1024 + c0;
  const size_t aw1 = (size_t)(toksh[r1] & 0xFFF) * 1024 + c1;
  const size_t bw0 = ((size_t)(h * 128 + r0) * 8 + e) * 1024 + c0;
  const size_t bw1 = ((size_t)(h * 128 + r1) * 8 + e) * 1024 + c1;
  const int csl = (lg ^ ((lr + (lr >> 2)) & 3)) << 3;
  f4v acc[4][4] = {};
#define STG_VE(A, B, k0) do { \
    glds16(&Xb[aw0 + (k0)], &A[tid * 8]); \
    glds16(&Xb[aw1 + (k0)], &A[(tid + 256) * 8]); \
    glds16(&Vw[bw0 + (k0)], &B[tid * 8]); \
    glds16(&Vw[bw1 + (k0)], &B[(tid + 256) * 8]); \
  } while (0)
#define CMP_VE(A, B) do { \
    s8v af[4], bfr[4]; \
    _Pragma("unroll") for (int m = 0; m < 4; ++m) af[m] = *(const s8v*)&A[(wm * 64 + m * 16 + lr) * 32 + csl]; \
    _Pragma("unroll") for (int n = 0; n < 4; ++n) bfr[n] = *(const s8v*)&B[(wn * 64 + n * 16 + lr) * 32 + csl]; \
    _Pragma("unroll") for (int m = 0; m < 4; ++m) \
      _Pragma("unroll") for (int n = 0; n < 4; ++n) \
        acc[m][n] = __builtin_amdgcn_mfma_f32_16x16x32_bf16(af[m], bfr[n], acc[m][n], 0, 0, 0); \
  } while (0)
  STG_VE(Ash0, Bsh0, 0);
  for (int kt = 0; kt < 32; kt += 2) {
    WAITB();
    if (kt + 1 < 32) STG_VE(Ash1, Bsh1, (kt + 1) * 32);
    CMP_VE(Ash0, Bsh0);
    WAITB();
    if (kt + 2 < 32) STG_VE(Ash0, Bsh0, (kt + 2) * 32);
    CMP_VE(Ash1, Bsh1);
  }
#undef STG_VE
#undef CMP_VE
#pragma unroll
  for (int m = 0; m < 4; ++m) {
#pragma unroll
    for (int j = 0; j < 4; ++j) {
      int row = wm * 64 + m * 16 + lg * 4 + j;
      int ar = tile * 128 + row;
      if (ar < cnt) {
        int entry = toksh[row];
        int tok = entry & 0xFFF;
        u16* dst = (entry & 0x8000) ? VpB : VpA;
        float g = gsh[row];
#pragma unroll
        for (int n = 0; n < 4; ++n) {
          int p = wn * 64 + n * 16 + lr;
          dst[(size_t)tok * 1024 + h * 128 + p] = bf16_rne(g * acc[m][n][j]);
        }
      }
    }
  }
}

// ---------------- vadd_transpose: VT[bh][p][s] = VpA[t][hp] + VpB[t][hp] ----------------
__global__ void vadd_transpose(const u16* __restrict__ VpA, const u16* __restrict__ VpB,
                               u16* __restrict__ VT) {
  __shared__ u16 tile[64][136];
  const int sb = blockIdx.x, bh = blockIdx.y;
  const int b = bh >> 3, h = bh & 7;
  const int tid = threadIdx.x;
#pragma unroll
  for (int it = 0; it < 4; ++it) {
    int idx = tid + it * 256;
    int r = idx >> 4, c8 = (idx & 15) << 3;
    size_t off = (size_t)(b * 2048 + sb * 64 + r) * 1024 + h * 128 + c8;
    s8v va = *(const s8v*)&VpA[off];
    s8v vb = *(const s8v*)&VpB[off];
    s8v o;
#pragma unroll
    for (int j = 0; j < 8; ++j) o[j] = (short)bf16_rne(bf2f((u16)va[j]) + bf2f((u16)vb[j]));
    *(s8v*)&tile[r][c8] = o;
  }
  __syncthreads();
#pragma unroll
  for (int it = 0; it < 8; ++it) {
    int idx = tid + it * 256;
    int p = idx >> 4, c4 = (idx & 15) << 2;
    us4 o;
#pragma unroll
    for (int j = 0; j < 4; ++j) o[j] = tile[c4 + j][p];
    *(us4*)&VT[((size_t)bh * 128 + p) * 2048 + sb * 64 + c4] = o;
  }
}

// ---------------- attention (flash-style) ----------------
__global__ __launch_bounds__(256, 2) void attn(
    const u16* __restrict__ Q, const u16* __restrict__ K,
    const u16* __restrict__ VT, u16* __restrict__ CTX) {
  __shared__ u16 Kt[64 * 136];
  __shared__ u16 Vt[128 * 72];
  __shared__ u16 Pl[4][16 * 72];
  const int qb = blockIdx.x, bh = blockIdx.y;
  const int tid = threadIdx.x;
  const int wave = tid >> 6, lane = tid & 63;
  const int lg = lane >> 4, lr = lane & 15;
  const size_t base = (size_t)bh * 2048 * 128;
  const int q0 = qb * 64 + wave * 16;
  s8v qf[4];
#pragma unroll
  for (int ks = 0; ks < 4; ++ks)
    qf[ks] = *(const s8v*)&Q[base + (size_t)(q0 + lr) * 128 + ks * 32 + lg * 8];
  f4v cacc[8] = {};
  float mrun = -1e30f, ssum = 0.f;
  for (int kb = 0; kb < 32; ++kb) {
    __syncthreads();
#pragma unroll
    for (int i = 0; i < 4; ++i) {
      int idx = tid + i * 256;
      int r = idx >> 4, c8 = (idx & 15) << 3;
      *(s8v*)&Kt[r * 136 + c8] = *(const s8v*)&K[base + (size_t)(kb * 64 + r) * 128 + c8];
    }
#pragma unroll
    for (int i = 0; i < 4; ++i) {
      int idx = tid + i * 256;
      int r = idx >> 3, c8 = (idx & 7) << 3;
      *(s8v*)&Vt[r * 72 + c8] = *(const s8v*)&VT[base + (size_t)r * 2048 + kb * 64 + c8];
    }
    __syncthreads();
    f4v sc[4] = {};
#pragma unroll
    for (int ks = 0; ks < 4; ++ks) {
#pragma unroll
      for (int m = 0; m < 4; ++m) {
        s8v ak = *(const s8v*)&Kt[(m * 16 + lr) * 136 + ks * 32 + lg * 8];
        sc[m] = __builtin_amdgcn_mfma_f32_16x16x32_bf16(ak, qf[ks], sc[m], 0, 0, 0);
      }
    }
    float tmax = -1e30f;
#pragma unroll
    for (int m = 0; m < 4; ++m)
#pragma unroll
      for (int j = 0; j < 4; ++j) {
        float v = sc[m][j] * ATT_SCALE;
        sc[m][j] = v;
        tmax = fmaxf(tmax, v);
      }
    tmax = fmaxf(tmax, __shfl_xor(tmax, 16));
    tmax = fmaxf(tmax, __shfl_xor(tmax, 32));
    float mnew = fmaxf(mrun, tmax);
    float f = __expf(mrun - mnew);
    mrun = mnew;
    float psum = 0.f;
#pragma unroll
    for (int m = 0; m < 4; ++m) {
      us4 pk;
#pragma unroll
      for (int j = 0; j < 4; ++j) {
        float pe = __expf(sc[m][j] - mnew);
        psum += pe;
        pk[j] = bf16_rne(pe);
      }
      *(us4*)&Pl[wave][lr * 72 + m * 16 + lg * 4] = pk;
    }
    psum += __shfl_xor(psum, 16);
    psum += __shfl_xor(psum, 32);
    ssum = ssum * f + psum;
#pragma unroll
    for (int mr = 0; mr < 8; ++mr)
#pragma unroll
      for (int j = 0; j < 4; ++j) cacc[mr][j] *= f;
#pragma unroll
    for (int ks = 0; ks < 2; ++ks) {
      s8v bp = *(const s8v*)&Pl[wave][lr * 72 + ks * 32 + lg * 8];
#pragma unroll
      for (int mr = 0; mr < 8; ++mr) {
        s8v av = *(const s8v*)&Vt[(mr * 16 + lr) * 72 + ks * 32 + lg * 8];
        cacc[mr] = __builtin_amdgcn_mfma_f32_16x16x32_bf16(av, bp, cacc[mr], 0, 0, 0);
      }
    }
  }
  float rinv = 1.f / ssum;
#pragma unroll
  for (int mr = 0; mr < 8; ++mr) {
    us4 pk;
#pragma unroll
    for (int j = 0; j < 4; ++j) pk[j] = bf16_rne(cacc[mr][j] * rinv);
    *(us4*)&CTX[base + (size_t)(q0 + lr) * 128 + mr * 16 + lg * 4] = pk;
  }
}

// ---------------- pregate: CTXG[t][he*128+p] = gate_o[t,he] * ctx[t,h,p] ----------------
__global__ __launch_bounds__(256) void pregate(
    const u16* __restrict__ CTX, const int2* __restrict__ Toi, const float2* __restrict__ Tog,
    u16* __restrict__ CTXG) {
  const int t = blockIdx.x;
  const int tid = threadIdx.x;
  __shared__ float gsh[64];
  if (tid < 64) {
    int h = tid >> 3, e = tid & 7;
    int2 ei = Toi[t * 8 + h];
    float2 gg = Tog[t * 8 + h];
    gsh[tid] = (e == ei.x) ? gg.x : ((e == ei.y) ? gg.y : 0.f);
  }
  __syncthreads();
  const int b = t >> 11, s = t & 2047;
#pragma unroll
  for (int c = 0; c < 4; ++c) {
    int chunk = tid + c * 256;            // 0..1023 chunks of 8 elems
    int he = chunk >> 4, p8 = (chunk & 15) << 3;
    int h = he >> 3;
    float g = gsh[he];
    s8v o;
    if (g != 0.f) {
      s8v v = *(const s8v*)&CTX[((size_t)(b * 8 + h) * 2048 + s) * 128 + p8];
#pragma unroll
      for (int j = 0; j < 8; ++j) o[j] = (short)bf16_rne(bf2f((u16)v[j]) * g);
    } else {
#pragma unroll
      for (int j = 0; j < 8; ++j) o[j] = 0;
    }
    *(s8v*)&CTXG[(size_t)t * 8192 + chunk * 8] = o;
  }
}

// ---------------- O projection: dense 128^2, dbuf prefetch + swizzle, split-K=2 ----------------
// grid (32 tb, 8 db, 2 kz). kz=0 -> OUT fp32 direct; kz=1 -> partials (2 x 8MB halves).
__global__ __launch_bounds__(256) void gemm_o_dense(
    const u16* __restrict__ CTXG, const u16* __restrict__ Ow /*[d][8192]*/,
    float* __restrict__ OUT, float* __restrict__ OP1a, float* __restrict__ OP1b) {
  __shared__ u16 Ash0[128 * 32], Ash1[128 * 32];
  __shared__ u16 Bsh0[128 * 32], Bsh1[128 * 32];
  const int tb = blockIdx.x, db = blockIdx.y, kz = blockIdx.z;
  const int tid = threadIdx.x;
  const int wave = tid >> 6, lane = tid & 63;
  const int wm = wave >> 1, wn = wave & 1;
  const int lg = lane >> 4, lr = lane & 15;
  const size_t kbase = (size_t)kz * 4096;
  const int r0 = tid >> 2, r1 = (tid + 256) >> 2;
  const int c0 = swzcol(tid), c1 = swzcol(tid + 256);
  const size_t aw0 = (size_t)(tb * 128 + r0) * 8192 + kbase + c0;
  const size_t aw1 = (size_t)(tb * 128 + r1) * 8192 + kbase + c1;
  const size_t bw0 = (size_t)(db * 128 + r0) * 8192 + kbase + c0;
  const size_t bw1 = (size_t)(db * 128 + r1) * 8192 + kbase + c1;
  const int csl = (lg ^ ((lr + (lr >> 2)) & 3)) << 3;
  f4v acc[4][4] = {};
#define STG_O(A, B, k0) do { \
    glds16(&CTXG[aw0 + (k0)], &A[tid * 8]); \
    glds16(&CTXG[aw1 + (k0)], &A[(tid + 256) * 8]); \
    glds16(&Ow[bw0 + (k0)], &B[tid * 8]); \
    glds16(&Ow[bw1 + (k0)], &B[(tid + 256) * 8]); \
  } while (0)
#define CMP_O(A, B) do { \
    s8v af[4], bfr[4]; \
    _Pragma("unroll") for (int m = 0; m < 4; ++m) af[m] = *(const s8v*)&A[(wm * 64 + m * 16 + lr) * 32 + csl]; \
    _Pragma("unroll") for (int n = 0; n < 4; ++n) bfr[n] = *(const s8v*)&B[(wn * 64 + n * 16 + lr) * 32 + csl]; \
    _Pragma("unroll") for (int m = 0; m < 4; ++m) \
      _Pragma("unroll") for (int n = 0; n < 4; ++n) \
        acc[m][n] = __builtin_amdgcn_mfma_f32_16x16x32_bf16(af[m], bfr[n], acc[m][n], 0, 0, 0); \
  } while (0)
  STG_O(Ash0, Bsh0, 0);
  for (int kt = 0; kt < 128; kt += 2) {
    WAITB();
    if (kt + 1 < 128) STG_O(Ash1, Bsh1, (kt + 1) * 32);
    CMP_O(Ash0, Bsh0);
    WAITB();
    if (kt + 2 < 128) STG_O(Ash0, Bsh0, (kt + 2) * 32);
    CMP_O(Ash1, Bsh1);
  }
#undef STG_O
#undef CMP_O
  float* OP;
  if (kz == 0) OP = OUT;
  else OP = (tb < 16) ? OP1a : OP1b;
  const int toff = (kz == 0) ? tb * 128 : (tb & 15) * 128;
#pragma unroll
  for (int m = 0; m < 4; ++m) {
    int t = toff + wm * 64 + m * 16 + lg * 4;
#pragma unroll
    for (int n = 0; n < 4; ++n) {
      int d = db * 128 + wn * 64 + n * 16 + lr;
#pragma unroll
      for (int j = 0; j < 4; ++j)
        OP[(size_t)(t + j) * 1024 + d] = acc[m][n][j];
    }
  }
}

// ---------------- OUT += partial (split halves) ----------------
__global__ void add_inplace(float* __restrict__ OUT, const float* __restrict__ P0,
                            const float* __restrict__ P1) {
  size_t i = ((size_t)blockIdx.x * 256 + threadIdx.x) * 4;  // 4M floats
  const float* P = (i < 2097152) ? (P0 + i) : (P1 + (i - 2097152));
  float4 a = *(const float4*)&OUT[i];
  float4 b = *(const float4*)P;
  *(float4*)&OUT[i] = make_float4(a.x + b.x, a.y + b.y, a.z + b.z, a.w + b.w);
}

extern "C" void kernel_launch(void* const* d_in, const int* in_sizes, int n_in,
                              void* d_out, int out_size, void* d_ws, size_t ws_size,
                              hipStream_t stream) {
  const float* x     = (const float*)d_in[0];
  const float* q_w   = (const float*)d_in[1];
  const float* k_w   = (const float*)d_in[2];
  const float* v_w   = (const float*)d_in[3];
  const float* o_w   = (const float*)d_in[4];
  const float* sel_v = (const float*)d_in[5];
  const float* sel_o = (const float*)d_in[6];
  const float* rs    = (const float*)d_in[7];

  char* ws = (char*)d_ws;
  const size_t MB = 1048576;
  const size_t KB = 1024;
  // Timeline / overlays (96 MB peak, proven ws >= 97.5 MB):
  u16*    xb    = (u16*)(ws);                        // [0,8M): xb -> ctx -> op1a
  u16*    ctx   = (u16*)(ws);
  float*  op1a  = (float*)(ws);
  u16*    qwb   = (u16*)(ws + 8 * MB);               // [8,10M) dead after gemm_qk
  u16*    kwb   = (u16*)(ws + 10 * MB);              // [10,12M)
  u16*    ctxg  = (u16*)(ws + 8 * MB);               // [8,72M) from pregate on
  u16*    vwT   = (u16*)(ws + 12 * MB);              // [12,28M) dead after gemm_v_e
  u16*    vt    = (u16*)(ws + 12 * MB);              // [12,20M) written after vwT dead
  u16*    vpA   = (u16*)(ws + 28 * MB);              // [28,36M) role-0 partials
  u16*    vpB   = (u16*)(ws + 36 * MB);              // [36,44M) role-1 partials
  u16*    qh    = (u16*)(ws + 49 * MB + 512 * KB);   // [49.5,57.5M)
  u16*    kh    = (u16*)(ws + 57 * MB + 512 * KB);   // [57.5,65.5M)
  int2*   tvi   = (int2*)(ws + 72 * MB);             // [72,80M): routing/bucket meta -> op1b
  float2* tvg   = (float2*)(ws + 72 * MB + 256 * KB);
  int2*   toi   = (int2*)(ws + 72 * MB + 512 * KB);
  float2* tog   = (float2*)(ws + 72 * MB + 768 * KB);
  int*    bcnt2 = (int*)(ws + 73 * MB);              // 256B (pad to 4K)
  u16*    btok2 = (u16*)(ws + 73 * MB + 4 * KB);     // 512K
  float*  bgate2= (float*)(ws + 73 * MB + 520 * KB); // 1M -> ends 73M+1544K
  float*  op1b  = (float*)(ws + 72 * MB);
  u16*    owT   = (u16*)(ws + 80 * MB);              // [80,96M) live until gemm_o_dense
  float*  outp  = (float*)d_out;

  hipLaunchKernelGGL(conv_qk, dim3(2048), dim3(256), 0, stream, q_w, k_w, qwb, kwb);
  hipLaunchKernelGGL(transpose_w, dim3(4, 32, 64), dim3(256), 0, stream, v_w, vwT, 0);
  hipLaunchKernelGGL(transpose_w, dim3(32, 4, 64), dim3(256), 0, stream, o_w, owT, 1);
  hipLaunchKernelGGL(routing, dim3(512), dim3(256), 0, stream, x, sel_v, sel_o, rs, tvi, tvg, toi, tog, xb);
  hipLaunchKernelGGL(build_buckets2, dim3(8), dim3(256), 0, stream, tvi, tvg, bcnt2, btok2, bgate2);
  hipLaunchKernelGGL(gemm_v_e, dim3(32, 64), dim3(256), 0, stream, xb, vwT, bcnt2, btok2, bgate2, vpA, vpB);
  hipLaunchKernelGGL(vadd_transpose, dim3(32, 16), dim3(256), 0, stream, vpA, vpB, vt);
  hipLaunchKernelGGL(gemm_qk, dim3(64, 8, 2), dim3(256), 0, stream, xb, qwb, kwb, qh, kh);
  hipLaunchKernelGGL(attn, dim3(32, 16), dim3(256), 0, stream, qh, kh, vt, ctx);
  hipLaunchKernelGGL(pregate, dim3(4096), dim3(256), 0, stream, ctx, toi, tog, ctxg);
  hipLaunchKernelGGL(gemm_o_dense, dim3(32, 8, 2), dim3(256), 0, stream, ctxg, owT, outp, op1a, op1b);
  hipLaunchKernelGGL(add_inplace, dim3(4096), dim3(256), 0, stream, outp, op1a, op1b);
}

// Round 10
// 380.908 us; speedup vs baseline: 1.6946x; 1.1090x over previous
//
#include <hip/hip_runtime.h>

// SwitchHeadCore: B=2,S=2048,D=1024,H=8,E=8,P=128,K=2(top-k). T = 4096.

typedef unsigned short u16;
typedef __attribute__((ext_vector_type(8))) short s8v;   // 8 x bf16 (MFMA A/B frag)
typedef __attribute__((ext_vector_type(4))) float f4v;   // MFMA C/D frag
typedef __attribute__((ext_vector_type(4))) unsigned short us4;

#define ATT_SCALE 0.08838834764831845f

__device__ inline u16 bf16_rne(float f) {
  union { float f; unsigned u; } v; v.f = f;
  unsigned r = v.u + 0x7fffu + ((v.u >> 16) & 1u);
  return (u16)(r >> 16);
}
__device__ inline float bf2f(u16 h) {
  union { unsigned u; float f; } v; v.u = ((unsigned)h) << 16;
  return v.f;
}

// async global->LDS, 16B per lane. Global src may be per-lane; LDS dest linear in lane order.
__device__ inline void glds16(const void* g, void* l) {
  __builtin_amdgcn_global_load_lds((const __attribute__((address_space(1))) void*)g,
                                   (__attribute__((address_space(3))) void*)l, 16, 0, 0);
}
// swizzled source column (u16 units) for staging lane index idx (rows of 32 u16, 4 slots of 8)
__device__ inline int swzcol(int idx) {
  int r = idx >> 2;
  return (((idx & 3) ^ ((r + (r >> 2)) & 3)) << 3);
}
#define WAITB() do { asm volatile("s_waitcnt vmcnt(0)" ::: "memory"); __syncthreads(); } while (0)

// ---------------- weight prep ----------------
__global__ void conv_qk(const float* __restrict__ Q, const float* __restrict__ K,
                        u16* __restrict__ Qb, u16* __restrict__ Kb) {
  int i = blockIdx.x * 256 + threadIdx.x;
  const float* src; u16* dst; int off;
  if (i < 262144) { src = Q; dst = Qb; off = i; }
  else            { src = K; dst = Kb; off = i - 262144; }
  float4 v = *(const float4*)&src[(size_t)off * 4];
  us4 o; o[0]=bf16_rne(v.x); o[1]=bf16_rne(v.y); o[2]=bf16_rne(v.z); o[3]=bf16_rne(v.w);
  *(us4*)&dst[(size_t)off * 4] = o;
}

// mode 0: v_w [he][1024 d][128 p] -> vwT [h][p][e][d]
// mode 1: o_w [he][128 p][1024 d] -> owT [d][he*128+p]
__global__ void transpose_w(const float* __restrict__ src, u16* __restrict__ dst, int mode) {
  __shared__ float tile[32][33];
  int he = blockIdx.z;
  int C = mode ? 1024 : 128;
  int r0 = blockIdx.y * 32, c0 = blockIdx.x * 32;
  int lc = threadIdx.x & 31, rr = threadIdx.x >> 5;
  const float* s = src + (size_t)he * 131072;
#pragma unroll
  for (int i = 0; i < 4; ++i) {
    int r = rr + i * 8;
    tile[r][lc] = s[(size_t)(r0 + r) * C + c0 + lc];
  }
  __syncthreads();
#pragma unroll
  for (int i = 0; i < 4; ++i) {
    int c = rr + i * 8;
    float v = tile[lc][c];
    size_t a;
    if (mode) a = (size_t)(c0 + c) * 8192 + (size_t)he * 128 + (r0 + lc);
    else      a = (size_t)(he >> 3) * 1048576 + (size_t)(c0 + c) * 8192 + (size_t)(he & 7) * 1024 + (r0 + lc);
    dst[a] = bf16_rne(v);
  }
}

// ---------------- routing + x->bf16 ----------------
__global__ __launch_bounds__(256, 2) void routing(
    const float* __restrict__ X, const float* __restrict__ SelV, const float* __restrict__ SelO,
    const float* __restrict__ RS, int2* __restrict__ Tvi, float2* __restrict__ Tvg,
    int2* __restrict__ Toi, float2* __restrict__ Tog, u16* __restrict__ Xb) {
  __shared__ float xs[8][1024];
  __shared__ float lgs[8][128];
  int t0 = blockIdx.x * 8;
  int tid = threadIdx.x;
  for (int i = tid; i < 2048; i += 256) {
    int row = i >> 8, c = (i & 255) * 4;
    float4 v = *(const float4*)&X[(size_t)(t0 + row) * 1024 + c];
    *(float4*)&xs[row][c] = v;
    us4 o; o[0]=bf16_rne(v.x); o[1]=bf16_rne(v.y); o[2]=bf16_rne(v.z); o[3]=bf16_rne(v.w);
    *(us4*)&Xb[(size_t)(t0 + row) * 1024 + c] = o;
  }
  __syncthreads();
  {
    int widx = tid & 127, tg = tid >> 7;
    const float* w = (widx < 64) ? (SelV + (size_t)widx * 1024) : (SelO + (size_t)(widx - 64) * 1024);
    float acc[4] = {0.f, 0.f, 0.f, 0.f};
    for (int k = 0; k < 1024; k += 4) {
      float4 wv = *(const float4*)&w[k];
#pragma unroll
      for (int t = 0; t < 4; ++t) {
        float4 xv = *(const float4*)&xs[tg * 4 + t][k];
        acc[t] += wv.x * xv.x + wv.y * xv.y + wv.z * xv.z + wv.w * xv.w;
      }
    }
#pragma unroll
    for (int t = 0; t < 4; ++t) lgs[tg * 4 + t][widx] = acc[t];
  }
  __syncthreads();
  if (tid < 128) {
    float rs = RS[0];
    int tok = tid >> 4, which = (tid >> 3) & 1, h = tid & 7;
    float p[8];
#pragma unroll
    for (int e = 0; e < 8; ++e)
      p[e] = 1.f / (1.f + __expf(-lgs[tok][which * 64 + h * 8 + e]));
    float v1 = -1.f; int i1 = -1;
#pragma unroll
    for (int e = 0; e < 8; ++e) if (p[e] > v1) { v1 = p[e]; i1 = e; }
    float v2 = -1.f; int i2 = -1;
#pragma unroll
    for (int e = 0; e < 8; ++e) if (e != i1 && p[e] > v2) { v2 = p[e]; i2 = e; }
    float ssum = fmaxf(v1 + v2, 1e-9f);
    float g1 = v1 / ssum * rs, g2 = v2 / ssum * rs;
    int t = t0 + tok;
    int lo, hi; float glo, ghi;
    if (i1 < i2) { lo = i1; hi = i2; glo = g1; ghi = g2; }
    else         { lo = i2; hi = i1; glo = g2; ghi = g1; }
    if (which) { Toi[t * 8 + h] = make_int2(lo, hi); Tog[t * 8 + h] = make_float2(glo, ghi); }
    else       { Tvi[t * 8 + h] = make_int2(lo, hi); Tvg[t * 8 + h] = make_float2(glo, ghi); }
  }
}

// ---------------- V bucket build v3: wave-aggregated, LDS counters, 1 block/head ----------------
__global__ __launch_bounds__(256) void build_buckets2(
    const int2* __restrict__ Tvi, const float2* __restrict__ Tvg,
    int* __restrict__ bcnt, u16* __restrict__ btok, float* __restrict__ bgate) {
  const int h = blockIdx.x;
  const int tid = threadIdx.x;
  const int lane = tid & 63;
  __shared__ int cnt[8];
  if (tid < 8) cnt[tid] = 0;
  __syncthreads();
  for (int chunk = 0; chunk < 16; ++chunk) {
    int t = chunk * 256 + tid;
    int2 e = Tvi[t * 8 + h];
    float2 g = Tvg[t * 8 + h];
#pragma unroll
    for (int role = 0; role < 2; ++role) {
      int mye = role ? e.y : e.x;
      float myg = role ? g.y : g.x;
      u16 entry = role ? (u16)(t | 0x8000) : (u16)t;
#pragma unroll
      for (int ee = 0; ee < 8; ++ee) {
        unsigned long long mask = __ballot(mye == ee);
        if (mye == ee) {
          int prefix = __popcll(mask & ((1ull << lane) - 1ull));
          int leader = __ffsll((unsigned long long)mask) - 1;
          int base = 0;
          if (lane == leader) base = atomicAdd(&cnt[ee], (int)__popcll(mask));
          base = __shfl(base, leader);
          int pos = base + prefix;
          btok[(h * 8 + ee) * 4096 + pos] = entry;
          bgate[(h * 8 + ee) * 4096 + pos] = myg;
        }
      }
    }
  }
  __syncthreads();
  if (tid < 8) bcnt[h * 8 + tid] = cnt[tid];
}

// ---------------- Q/K projection GEMM: 64x128 tile, dbuf prefetch + swizzle ----------------
// grid (64 tb, 8 nb, 2 qk)
__global__ __launch_bounds__(256) void gemm_qk(
    const u16* __restrict__ Xb, const u16* __restrict__ Wq, const u16* __restrict__ Wk,
    u16* __restrict__ Qo, u16* __restrict__ Ko) {
  __shared__ u16 Ash0[64 * 32], Ash1[64 * 32];
  __shared__ u16 Bsh0[128 * 32], Bsh1[128 * 32];
  const int tb = blockIdx.x, nb = blockIdx.y;
  const u16* W = blockIdx.z ? Wk : Wq;
  u16* Out = blockIdx.z ? Ko : Qo;
  const int tid = threadIdx.x;
  const int wave = tid >> 6, lane = tid & 63;
  const int lg = lane >> 4, lr = lane & 15;
  const int r0 = tid >> 2, r1 = (tid + 256) >> 2;
  const int c0 = swzcol(tid), c1 = swzcol(tid + 256);
  const size_t aw  = (size_t)(tb * 64 + r0) * 1024 + c0;
  const size_t bw0 = (size_t)(nb * 128 + r0) * 1024 + c0;
  const size_t bw1 = (size_t)(nb * 128 + r1) * 1024 + c1;
  const int csl = (lg ^ ((lr + (lr >> 2)) & 3)) << 3;
  f4v acc[4][2] = {};
#define STG_QK(A, B, k0) do { \
    glds16(&Xb[aw + (k0)], &A[tid * 8]); \
    glds16(&W[bw0 + (k0)], &B[tid * 8]); \
    glds16(&W[bw1 + (k0)], &B[(tid + 256) * 8]); \
  } while (0)
#define CMP_QK(A, B) do { \
    s8v af[4], bfr[2]; \
    _Pragma("unroll") for (int m = 0; m < 4; ++m) af[m] = *(const s8v*)&A[(m * 16 + lr) * 32 + csl]; \
    _Pragma("unroll") for (int n = 0; n < 2; ++n) bfr[n] = *(const s8v*)&B[(wave * 32 + n * 16 + lr) * 32 + csl]; \
    _Pragma("unroll") for (int m = 0; m < 4; ++m) \
      _Pragma("unroll") for (int n = 0; n < 2; ++n) \
        acc[m][n] = __builtin_amdgcn_mfma_f32_16x16x32_bf16(af[m], bfr[n], acc[m][n], 0, 0, 0); \
  } while (0)
  STG_QK(Ash0, Bsh0, 0);
  for (int kt = 0; kt < 32; kt += 2) {
    WAITB();
    if (kt + 1 < 32) STG_QK(Ash1, Bsh1, (kt + 1) * 32);
    CMP_QK(Ash0, Bsh0);
    WAITB();
    if (kt + 2 < 32) STG_QK(Ash0, Bsh0, (kt + 2) * 32);
    CMP_QK(Ash1, Bsh1);
  }
#undef STG_QK
#undef CMP_QK
#pragma unroll
  for (int m = 0; m < 4; ++m) {
    int tbase = tb * 64 + m * 16 + lg * 4;
    int b = tbase >> 11, s = tbase & 2047;
#pragma unroll
    for (int n = 0; n < 2; ++n) {
      int p = wave * 32 + n * 16 + lr;
      size_t base = ((size_t)(b * 8 + nb) * 2048 + s) * 128 + p;
#pragma unroll
      for (int j = 0; j < 4; ++j)
        Out[base + (size_t)j * 128] = bf16_rne(acc[m][n][j]);
    }
  }
}

// ---------------- V expert GEMM v3: per-(h,e) buckets, 128x128 tile, role-split partials ----------------
// grid (32 tiles, 64 buckets) with XCD-aware remap: XCD k owns buckets 8k..8k+7 (B panels L2-resident).
__global__ __launch_bounds__(256) void gemm_v_e(
    const u16* __restrict__ Xb, const u16* __restrict__ Vw /*[h][p][e][d]*/,
    const int* __restrict__ bcnt, const u16* __restrict__ btok,
    const float* __restrict__ bgate, u16* __restrict__ VpA, u16* __restrict__ VpB) {
  const int id = blockIdx.x + 32 * blockIdx.y;
  const int xk = id & 7, j = id >> 3;          // j in 0..255
  const int bucket = 8 * xk + (j & 7);
  const int tile = j >> 3;                     // 0..31
  const int h = bucket >> 3, e = bucket & 7;
  const int cnt = bcnt[bucket];
  if (tile * 128 >= cnt) return;
  __shared__ u16 Ash0[128 * 32], Ash1[128 * 32];
  __shared__ u16 Bsh0[128 * 32], Bsh1[128 * 32];
  __shared__ int toksh[128];
  __shared__ float gsh[128];
  const int tid = threadIdx.x;
  if (tid < 128) {
    int ar = tile * 128 + tid;
    if (ar < cnt) {
      toksh[tid] = btok[bucket * 4096 + ar];
      gsh[tid] = bgate[bucket * 4096 + ar];
    } else { toksh[tid] = 0; gsh[tid] = 0.f; }
  }
  __syncthreads();
  const int wave = tid >> 6, lane = tid & 63;
  const int wm = wave >> 1, wn = wave & 1;
  const int lg = lane >> 4, lr = lane & 15;
  const int r0 = tid >> 2, r1 = (tid + 256) >> 2;
  const int c0 = swzcol(tid), c1 = swzcol(tid + 256);
  const size_t aw0 = (size_t)(toksh[r0] & 0xFFF) * 1024 + c0;
  const size_t aw1 = (size_t)(toksh[r1] & 0xFFF) * 1024 + c1;
  const size_t bw0 = ((size_t)(h * 128 + r0) * 8 + e) * 1024 + c0;
  const size_t bw1 = ((size_t)(h * 128 + r1) * 8 + e) * 1024 + c1;
  const int csl = (lg ^ ((lr + (lr >> 2)) & 3)) << 3;
  f4v acc[4][4] = {};
#define STG_VE(A, B, k0) do { \
    glds16(&Xb[aw0 + (k0)], &A[tid * 8]); \
    glds16(&Xb[aw1 + (k0)], &A[(tid + 256) * 8]); \
    glds16(&Vw[bw0 + (k0)], &B[tid * 8]); \
    glds16(&Vw[bw1 + (k0)], &B[(tid + 256) * 8]); \
  } while (0)
#define CMP_VE(A, B) do { \
    s8v af[4], bfr[4]; \
    _Pragma("unroll") for (int m = 0; m < 4; ++m) af[m] = *(const s8v*)&A[(wm * 64 + m * 16 + lr) * 32 + csl]; \
    _Pragma("unroll") for (int n = 0; n < 4; ++n) bfr[n] = *(const s8v*)&B[(wn * 64 + n * 16 + lr) * 32 + csl]; \
    _Pragma("unroll") for (int m = 0; m < 4; ++m) \
      _Pragma("unroll") for (int n = 0; n < 4; ++n) \
        acc[m][n] = __builtin_amdgcn_mfma_f32_16x16x32_bf16(af[m], bfr[n], acc[m][n], 0, 0, 0); \
  } while (0)
  STG_VE(Ash0, Bsh0, 0);
  for (int kt = 0; kt < 32; kt += 2) {
    WAITB();
    if (kt + 1 < 32) STG_VE(Ash1, Bsh1, (kt + 1) * 32);
    CMP_VE(Ash0, Bsh0);
    WAITB();
    if (kt + 2 < 32) STG_VE(Ash0, Bsh0, (kt + 2) * 32);
    CMP_VE(Ash1, Bsh1);
  }
#undef STG_VE
#undef CMP_VE
#pragma unroll
  for (int m = 0; m < 4; ++m) {
#pragma unroll
    for (int j2 = 0; j2 < 4; ++j2) {
      int row = wm * 64 + m * 16 + lg * 4 + j2;
      int ar = tile * 128 + row;
      if (ar < cnt) {
        int entry = toksh[row];
        int tok = entry & 0xFFF;
        u16* dst = (entry & 0x8000) ? VpB : VpA;
        float g = gsh[row];
#pragma unroll
        for (int n = 0; n < 4; ++n) {
          int p = wn * 64 + n * 16 + lr;
          dst[(size_t)tok * 1024 + h * 128 + p] = bf16_rne(g * acc[m][n][j2]);
        }
      }
    }
  }
}

// ---------------- vadd_transpose: VT[bh][p][s] = VpA[t][hp] + VpB[t][hp] ----------------
__global__ void vadd_transpose(const u16* __restrict__ VpA, const u16* __restrict__ VpB,
                               u16* __restrict__ VT) {
  __shared__ u16 tile[64][136];
  const int sb = blockIdx.x, bh = blockIdx.y;
  const int b = bh >> 3, h = bh & 7;
  const int tid = threadIdx.x;
#pragma unroll
  for (int it = 0; it < 4; ++it) {
    int idx = tid + it * 256;
    int r = idx >> 4, c8 = (idx & 15) << 3;
    size_t off = (size_t)(b * 2048 + sb * 64 + r) * 1024 + h * 128 + c8;
    s8v va = *(const s8v*)&VpA[off];
    s8v vb = *(const s8v*)&VpB[off];
    s8v o;
#pragma unroll
    for (int j = 0; j < 8; ++j) o[j] = (short)bf16_rne(bf2f((u16)va[j]) + bf2f((u16)vb[j]));
    *(s8v*)&tile[r][c8] = o;
  }
  __syncthreads();
#pragma unroll
  for (int it = 0; it < 8; ++it) {
    int idx = tid + it * 256;
    int p = idx >> 4, c4 = (idx & 15) << 2;
    us4 o;
#pragma unroll
    for (int j = 0; j < 4; ++j) o[j] = tile[c4 + j][p];
    *(us4*)&VT[((size_t)bh * 128 + p) * 2048 + sb * 64 + c4] = o;
  }
}

// ---------------- attention (flash-style), XCD-aware remap + setprio ----------------
// 512 blocks: XCD k owns bh {2k, 2k+1} -> K/V working set 2MB, L2-resident per XCD.
__global__ __launch_bounds__(256, 2) void attn(
    const u16* __restrict__ Q, const u16* __restrict__ K,
    const u16* __restrict__ VT, u16* __restrict__ CTX) {
  __shared__ u16 Kt[64 * 136];
  __shared__ u16 Vt[128 * 72];
  __shared__ u16 Pl[4][16 * 72];
  const int id = blockIdx.x + 32 * blockIdx.y;
  const int xk = id & 7, j = id >> 3;          // j in 0..63
  const int bh = 2 * xk + (j >> 5);
  const int qb = j & 31;
  const int tid = threadIdx.x;
  const int wave = tid >> 6, lane = tid & 63;
  const int lg = lane >> 4, lr = lane & 15;
  const size_t base = (size_t)bh * 2048 * 128;
  const int q0 = qb * 64 + wave * 16;
  s8v qf[4];
#pragma unroll
  for (int ks = 0; ks < 4; ++ks)
    qf[ks] = *(const s8v*)&Q[base + (size_t)(q0 + lr) * 128 + ks * 32 + lg * 8];
  f4v cacc[8] = {};
  float mrun = -1e30f, ssum = 0.f;
  for (int kb = 0; kb < 32; ++kb) {
    __syncthreads();
#pragma unroll
    for (int i = 0; i < 4; ++i) {
      int idx = tid + i * 256;
      int r = idx >> 4, c8 = (idx & 15) << 3;
      *(s8v*)&Kt[r * 136 + c8] = *(const s8v*)&K[base + (size_t)(kb * 64 + r) * 128 + c8];
    }
#pragma unroll
    for (int i = 0; i < 4; ++i) {
      int idx = tid + i * 256;
      int r = idx >> 3, c8 = (idx & 7) << 3;
      *(s8v*)&Vt[r * 72 + c8] = *(const s8v*)&VT[base + (size_t)r * 2048 + kb * 64 + c8];
    }
    __syncthreads();
    f4v sc[4] = {};
    __builtin_amdgcn_s_setprio(1);
#pragma unroll
    for (int ks = 0; ks < 4; ++ks) {
#pragma unroll
      for (int m = 0; m < 4; ++m) {
        s8v ak = *(const s8v*)&Kt[(m * 16 + lr) * 136 + ks * 32 + lg * 8];
        sc[m] = __builtin_amdgcn_mfma_f32_16x16x32_bf16(ak, qf[ks], sc[m], 0, 0, 0);
      }
    }
    __builtin_amdgcn_s_setprio(0);
    float tmax = -1e30f;
#pragma unroll
    for (int m = 0; m < 4; ++m)
#pragma unroll
      for (int j2 = 0; j2 < 4; ++j2) {
        float v = sc[m][j2] * ATT_SCALE;
        sc[m][j2] = v;
        tmax = fmaxf(tmax, v);
      }
    tmax = fmaxf(tmax, __shfl_xor(tmax, 16));
    tmax = fmaxf(tmax, __shfl_xor(tmax, 32));
    float mnew = fmaxf(mrun, tmax);
    float f = __expf(mrun - mnew);
    mrun = mnew;
    float psum = 0.f;
#pragma unroll
    for (int m = 0; m < 4; ++m) {
      us4 pk;
#pragma unroll
      for (int j2 = 0; j2 < 4; ++j2) {
        float pe = __expf(sc[m][j2] - mnew);
        psum += pe;
        pk[j2] = bf16_rne(pe);
      }
      *(us4*)&Pl[wave][lr * 72 + m * 16 + lg * 4] = pk;
    }
    psum += __shfl_xor(psum, 16);
    psum += __shfl_xor(psum, 32);
    ssum = ssum * f + psum;
#pragma unroll
    for (int mr = 0; mr < 8; ++mr)
#pragma unroll
      for (int j2 = 0; j2 < 4; ++j2) cacc[mr][j2] *= f;
    __builtin_amdgcn_s_setprio(1);
#pragma unroll
    for (int ks = 0; ks < 2; ++ks) {
      s8v bp = *(const s8v*)&Pl[wave][lr * 72 + ks * 32 + lg * 8];
#pragma unroll
      for (int mr = 0; mr < 8; ++mr) {
        s8v av = *(const s8v*)&Vt[(mr * 16 + lr) * 72 + ks * 32 + lg * 8];
        cacc[mr] = __builtin_amdgcn_mfma_f32_16x16x32_bf16(av, bp, cacc[mr], 0, 0, 0);
      }
    }
    __builtin_amdgcn_s_setprio(0);
  }
  float rinv = 1.f / ssum;
#pragma unroll
  for (int mr = 0; mr < 8; ++mr) {
    us4 pk;
#pragma unroll
    for (int j2 = 0; j2 < 4; ++j2) pk[j2] = bf16_rne(cacc[mr][j2] * rinv);
    *(us4*)&CTX[base + (size_t)(q0 + lr) * 128 + mr * 16 + lg * 4] = pk;
  }
}

// ---------------- pregate: CTXG[t][he*128+p] = gate_o[t,he] * ctx[t,h,p] ----------------
__global__ __launch_bounds__(256) void pregate(
    const u16* __restrict__ CTX, const int2* __restrict__ Toi, const float2* __restrict__ Tog,
    u16* __restrict__ CTXG) {
  const int t = blockIdx.x;
  const int tid = threadIdx.x;
  __shared__ float gsh[64];
  if (tid < 64) {
    int h = tid >> 3, e = tid & 7;
    int2 ei = Toi[t * 8 + h];
    float2 gg = Tog[t * 8 + h];
    gsh[tid] = (e == ei.x) ? gg.x : ((e == ei.y) ? gg.y : 0.f);
  }
  __syncthreads();
  const int b = t >> 11, s = t & 2047;
#pragma unroll
  for (int c = 0; c < 4; ++c) {
    int chunk = tid + c * 256;            // 0..1023 chunks of 8 elems
    int he = chunk >> 4, p8 = (chunk & 15) << 3;
    int h = he >> 3;
    float g = gsh[he];
    s8v o;
    if (g != 0.f) {
      s8v v = *(const s8v*)&CTX[((size_t)(b * 8 + h) * 2048 + s) * 128 + p8];
#pragma unroll
      for (int j = 0; j < 8; ++j) o[j] = (short)bf16_rne(bf2f((u16)v[j]) * g);
    } else {
#pragma unroll
      for (int j = 0; j < 8; ++j) o[j] = 0;
    }
    *(s8v*)&CTXG[(size_t)t * 8192 + chunk * 8] = o;
  }
}

// ---------------- O projection: dense 128^2, dbuf prefetch + swizzle, split-K=2 ----------------
// grid (32,8,2) with XCD remap: XCD k owns db=k -> 2MB owT panel L2-resident.
__global__ __launch_bounds__(256) void gemm_o_dense(
    const u16* __restrict__ CTXG, const u16* __restrict__ Ow /*[d][8192]*/,
    float* __restrict__ OUT, float* __restrict__ OP1a, float* __restrict__ OP1b) {
  __shared__ u16 Ash0[128 * 32], Ash1[128 * 32];
  __shared__ u16 Bsh0[128 * 32], Bsh1[128 * 32];
  const int id = blockIdx.x + 32 * blockIdx.y + 256 * blockIdx.z;
  const int xk = id & 7, j = id >> 3;          // j in 0..63
  const int db = xk;
  const int tb = j & 31;
  const int kz = j >> 5;
  const int tid = threadIdx.x;
  const int wave = tid >> 6, lane = tid & 63;
  const int wm = wave >> 1, wn = wave & 1;
  const int lg = lane >> 4, lr = lane & 15;
  const size_t kbase = (size_t)kz * 4096;
  const int r0 = tid >> 2, r1 = (tid + 256) >> 2;
  const int c0 = swzcol(tid), c1 = swzcol(tid + 256);
  const size_t aw0 = (size_t)(tb * 128 + r0) * 8192 + kbase + c0;
  const size_t aw1 = (size_t)(tb * 128 + r1) * 8192 + kbase + c1;
  const size_t bw0 = (size_t)(db * 128 + r0) * 8192 + kbase + c0;
  const size_t bw1 = (size_t)(db * 128 + r1) * 8192 + kbase + c1;
  const int csl = (lg ^ ((lr + (lr >> 2)) & 3)) << 3;
  f4v acc[4][4] = {};
#define STG_O(A, B, k0) do { \
    glds16(&CTXG[aw0 + (k0)], &A[tid * 8]); \
    glds16(&CTXG[aw1 + (k0)], &A[(tid + 256) * 8]); \
    glds16(&Ow[bw0 + (k0)], &B[tid * 8]); \
    glds16(&Ow[bw1 + (k0)], &B[(tid + 256) * 8]); \
  } while (0)
#define CMP_O(A, B) do { \
    s8v af[4], bfr[4]; \
    _Pragma("unroll") for (int m = 0; m < 4; ++m) af[m] = *(const s8v*)&A[(wm * 64 + m * 16 + lr) * 32 + csl]; \
    _Pragma("unroll") for (int n = 0; n < 4; ++n) bfr[n] = *(const s8v*)&B[(wn * 64 + n * 16 + lr) * 32 + csl]; \
    _Pragma("unroll") for (int m = 0; m < 4; ++m) \
      _Pragma("unroll") for (int n = 0; n < 4; ++n) \
        acc[m][n] = __builtin_amdgcn_mfma_f32_16x16x32_bf16(af[m], bfr[n], acc[m][n], 0, 0, 0); \
  } while (0)
  STG_O(Ash0, Bsh0, 0);
  for (int kt = 0; kt < 128; kt += 2) {
    WAITB();
    if (kt + 1 < 128) STG_O(Ash1, Bsh1, (kt + 1) * 32);
    CMP_O(Ash0, Bsh0);
    WAITB();
    if (kt + 2 < 128) STG_O(Ash0, Bsh0, (kt + 2) * 32);
    CMP_O(Ash1, Bsh1);
  }
#undef STG_O
#undef CMP_O
  float* OP;
  if (kz == 0) OP = OUT;
  else OP = (tb < 16) ? OP1a : OP1b;
  const int toff = (kz == 0) ? tb * 128 : (tb & 15) * 128;
#pragma unroll
  for (int m = 0; m < 4; ++m) {
    int t = toff + wm * 64 + m * 16 + lg * 4;
#pragma unroll
    for (int n = 0; n < 4; ++n) {
      int d = db * 128 + wn * 64 + n * 16 + lr;
#pragma unroll
      for (int j2 = 0; j2 < 4; ++j2)
        OP[(size_t)(t + j2) * 1024 + d] = acc[m][n][j2];
    }
  }
}

// ---------------- OUT += partial (split halves) ----------------
__global__ void add_inplace(float* __restrict__ OUT, const float* __restrict__ P0,
                            const float* __restrict__ P1) {
  size_t i = ((size_t)blockIdx.x * 256 + threadIdx.x) * 4;  // 4M floats
  const float* P = (i < 2097152) ? (P0 + i) : (P1 + (i - 2097152));
  float4 a = *(const float4*)&OUT[i];
  float4 b = *(const float4*)P;
  *(float4*)&OUT[i] = make_float4(a.x + b.x, a.y + b.y, a.z + b.z, a.w + b.w);
}

extern "C" void kernel_launch(void* const* d_in, const int* in_sizes, int n_in,
                              void* d_out, int out_size, void* d_ws, size_t ws_size,
                              hipStream_t stream) {
  const float* x     = (const float*)d_in[0];
  const float* q_w   = (const float*)d_in[1];
  const float* k_w   = (const float*)d_in[2];
  const float* v_w   = (const float*)d_in[3];
  const float* o_w   = (const float*)d_in[4];
  const float* sel_v = (const float*)d_in[5];
  const float* sel_o = (const float*)d_in[6];
  const float* rs    = (const float*)d_in[7];

  char* ws = (char*)d_ws;
  const size_t MB = 1048576;
  const size_t KB = 1024;
  // Timeline / overlays (96 MB peak, proven ws >= 97.5 MB):
  u16*    xb    = (u16*)(ws);                        // [0,8M): xb -> ctx -> op1a
  u16*    ctx   = (u16*)(ws);
  float*  op1a  = (float*)(ws);
  u16*    qwb   = (u16*)(ws + 8 * MB);               // [8,10M) dead after gemm_qk
  u16*    kwb   = (u16*)(ws + 10 * MB);              // [10,12M)
  u16*    ctxg  = (u16*)(ws + 8 * MB);               // [8,72M) from pregate on
  u16*    vwT   = (u16*)(ws + 12 * MB);              // [12,28M) dead after gemm_v_e
  u16*    vt    = (u16*)(ws + 12 * MB);              // [12,20M) written after vwT dead
  u16*    vpA   = (u16*)(ws + 28 * MB);              // [28,36M) role-0 partials
  u16*    vpB   = (u16*)(ws + 36 * MB);              // [36,44M) role-1 partials
  u16*    qh    = (u16*)(ws + 49 * MB + 512 * KB);   // [49.5,57.5M)
  u16*    kh    = (u16*)(ws + 57 * MB + 512 * KB);   // [57.5,65.5M)
  int2*   tvi   = (int2*)(ws + 72 * MB);             // [72,80M): routing/bucket meta -> op1b
  float2* tvg   = (float2*)(ws + 72 * MB + 256 * KB);
  int2*   toi   = (int2*)(ws + 72 * MB + 512 * KB);
  float2* tog   = (float2*)(ws + 72 * MB + 768 * KB);
  int*    bcnt2 = (int*)(ws + 73 * MB);              // 256B (pad to 4K)
  u16*    btok2 = (u16*)(ws + 73 * MB + 4 * KB);     // 512K
  float*  bgate2= (float*)(ws + 73 * MB + 520 * KB); // 1M -> ends 73M+1544K
  float*  op1b  = (float*)(ws + 72 * MB);
  u16*    owT   = (u16*)(ws + 80 * MB);              // [80,96M) live until gemm_o_dense
  float*  outp  = (float*)d_out;

  hipLaunchKernelGGL(conv_qk, dim3(2048), dim3(256), 0, stream, q_w, k_w, qwb, kwb);
  hipLaunchKernelGGL(transpose_w, dim3(4, 32, 64), dim3(256), 0, stream, v_w, vwT, 0);
  hipLaunchKernelGGL(transpose_w, dim3(32, 4, 64), dim3(256), 0, stream, o_w, owT, 1);
  hipLaunchKernelGGL(routing, dim3(512), dim3(256), 0, stream, x, sel_v, sel_o, rs, tvi, tvg, toi, tog, xb);
  hipLaunchKernelGGL(build_buckets2, dim3(8), dim3(256), 0, stream, tvi, tvg, bcnt2, btok2, bgate2);
  hipLaunchKernelGGL(gemm_v_e, dim3(32, 64), dim3(256), 0, stream, xb, vwT, bcnt2, btok2, bgate2, vpA, vpB);
  hipLaunchKernelGGL(vadd_transpose, dim3(32, 16), dim3(256), 0, stream, vpA, vpB, vt);
  hipLaunchKernelGGL(gemm_qk, dim3(64, 8, 2), dim3(256), 0, stream, xb, qwb, kwb, qh, kh);
  hipLaunchKernelGGL(attn, dim3(32, 16), dim3(256), 0, stream, qh, kh, vt, ctx);
  hipLaunchKernelGGL(pregate, dim3(4096), dim3(256), 0, stream, ctx, toi, tog, ctxg);
  hipLaunchKernelGGL(gemm_o_dense, dim3(32, 8, 2), dim3(256), 0, stream, ctxg, owT, outp, op1a, op1b);
  hipLaunchKernelGGL(add_inplace, dim3(4096), dim3(256), 0, stream, outp, op1a, op1b);
}

// Round 11
// 367.953 us; speedup vs baseline: 1.7543x; 1.0352x over previous
//
#include <hip/hip_runtime.h>

// SwitchHeadCore: B=2,S=2048,D=1024,H=8,E=8,P=128,K=2(top-k). T = 4096.

typedef unsigned short u16;
typedef __attribute__((ext_vector_type(8))) short s8v;   // 8 x bf16 (MFMA A/B frag)
typedef __attribute__((ext_vector_type(4))) float f4v;   // MFMA C/D frag
typedef __attribute__((ext_vector_type(4))) unsigned short us4;

#define ATT_SCALE 0.08838834764831845f

__device__ inline u16 bf16_rne(float f) {
  union { float f; unsigned u; } v; v.f = f;
  unsigned r = v.u + 0x7fffu + ((v.u >> 16) & 1u);
  return (u16)(r >> 16);
}
__device__ inline float bf2f(u16 h) {
  union { unsigned u; float f; } v; v.u = ((unsigned)h) << 16;
  return v.f;
}

// async global->LDS, 16B per lane. Global src may be per-lane; LDS dest linear in lane order.
__device__ inline void glds16(const void* g, void* l) {
  __builtin_amdgcn_global_load_lds((const __attribute__((address_space(1))) void*)g,
                                   (__attribute__((address_space(3))) void*)l, 16, 0, 0);
}
// swizzled source column (u16 units) for staging lane index idx (rows of 32 u16, 4 slots of 8)
__device__ inline int swzcol(int idx) {
  int r = idx >> 2;
  return (((idx & 3) ^ ((r + (r >> 2)) & 3)) << 3);
}
#define WAITB() do { asm volatile("s_waitcnt vmcnt(0)" ::: "memory"); __syncthreads(); } while (0)

// ---------------- weight prep ----------------
__global__ void conv_qk(const float* __restrict__ Q, const float* __restrict__ K,
                        u16* __restrict__ Qb, u16* __restrict__ Kb) {
  int i = blockIdx.x * 256 + threadIdx.x;
  const float* src; u16* dst; int off;
  if (i < 262144) { src = Q; dst = Qb; off = i; }
  else            { src = K; dst = Kb; off = i - 262144; }
  float4 v = *(const float4*)&src[(size_t)off * 4];
  us4 o; o[0]=bf16_rne(v.x); o[1]=bf16_rne(v.y); o[2]=bf16_rne(v.z); o[3]=bf16_rne(v.w);
  *(us4*)&dst[(size_t)off * 4] = o;
}

// mode 0: v_w [he][1024 d][128 p] -> vwT [h][p][e][d]
// mode 1: o_w [he][128 p][1024 d] -> owT [d][he*128+p]
__global__ void transpose_w(const float* __restrict__ src, u16* __restrict__ dst, int mode) {
  __shared__ float tile[32][33];
  int he = blockIdx.z;
  int C = mode ? 1024 : 128;
  int r0 = blockIdx.y * 32, c0 = blockIdx.x * 32;
  int lc = threadIdx.x & 31, rr = threadIdx.x >> 5;
  const float* s = src + (size_t)he * 131072;
#pragma unroll
  for (int i = 0; i < 4; ++i) {
    int r = rr + i * 8;
    tile[r][lc] = s[(size_t)(r0 + r) * C + c0 + lc];
  }
  __syncthreads();
#pragma unroll
  for (int i = 0; i < 4; ++i) {
    int c = rr + i * 8;
    float v = tile[lc][c];
    size_t a;
    if (mode) a = (size_t)(c0 + c) * 8192 + (size_t)he * 128 + (r0 + lc);
    else      a = (size_t)(he >> 3) * 1048576 + (size_t)(c0 + c) * 8192 + (size_t)(he & 7) * 1024 + (r0 + lc);
    dst[a] = bf16_rne(v);
  }
}

// ---------------- routing + x->bf16 ----------------
__global__ __launch_bounds__(256, 2) void routing(
    const float* __restrict__ X, const float* __restrict__ SelV, const float* __restrict__ SelO,
    const float* __restrict__ RS, int2* __restrict__ Tvi, float2* __restrict__ Tvg,
    int2* __restrict__ Toi, float2* __restrict__ Tog, u16* __restrict__ Xb) {
  __shared__ float xs[8][1024];
  __shared__ float lgs[8][128];
  int t0 = blockIdx.x * 8;
  int tid = threadIdx.x;
  for (int i = tid; i < 2048; i += 256) {
    int row = i >> 8, c = (i & 255) * 4;
    float4 v = *(const float4*)&X[(size_t)(t0 + row) * 1024 + c];
    *(float4*)&xs[row][c] = v;
    us4 o; o[0]=bf16_rne(v.x); o[1]=bf16_rne(v.y); o[2]=bf16_rne(v.z); o[3]=bf16_rne(v.w);
    *(us4*)&Xb[(size_t)(t0 + row) * 1024 + c] = o;
  }
  __syncthreads();
  {
    int widx = tid & 127, tg = tid >> 7;
    const float* w = (widx < 64) ? (SelV + (size_t)widx * 1024) : (SelO + (size_t)(widx - 64) * 1024);
    float acc[4] = {0.f, 0.f, 0.f, 0.f};
    for (int k = 0; k < 1024; k += 4) {
      float4 wv = *(const float4*)&w[k];
#pragma unroll
      for (int t = 0; t < 4; ++t) {
        float4 xv = *(const float4*)&xs[tg * 4 + t][k];
        acc[t] += wv.x * xv.x + wv.y * xv.y + wv.z * xv.z + wv.w * xv.w;
      }
    }
#pragma unroll
    for (int t = 0; t < 4; ++t) lgs[tg * 4 + t][widx] = acc[t];
  }
  __syncthreads();
  if (tid < 128) {
    float rs = RS[0];
    int tok = tid >> 4, which = (tid >> 3) & 1, h = tid & 7;
    float p[8];
#pragma unroll
    for (int e = 0; e < 8; ++e)
      p[e] = 1.f / (1.f + __expf(-lgs[tok][which * 64 + h * 8 + e]));
    float v1 = -1.f; int i1 = -1;
#pragma unroll
    for (int e = 0; e < 8; ++e) if (p[e] > v1) { v1 = p[e]; i1 = e; }
    float v2 = -1.f; int i2 = -1;
#pragma unroll
    for (int e = 0; e < 8; ++e) if (e != i1 && p[e] > v2) { v2 = p[e]; i2 = e; }
    float ssum = fmaxf(v1 + v2, 1e-9f);
    float g1 = v1 / ssum * rs, g2 = v2 / ssum * rs;
    int t = t0 + tok;
    int lo, hi; float glo, ghi;
    if (i1 < i2) { lo = i1; hi = i2; glo = g1; ghi = g2; }
    else         { lo = i2; hi = i1; glo = g2; ghi = g1; }
    if (which) { Toi[t * 8 + h] = make_int2(lo, hi); Tog[t * 8 + h] = make_float2(glo, ghi); }
    else       { Tvi[t * 8 + h] = make_int2(lo, hi); Tvg[t * 8 + h] = make_float2(glo, ghi); }
  }
}

// ---------------- V bucket build v3: wave-aggregated, LDS counters, 1 block/head ----------------
__global__ __launch_bounds__(256) void build_buckets2(
    const int2* __restrict__ Tvi, const float2* __restrict__ Tvg,
    int* __restrict__ bcnt, u16* __restrict__ btok, float* __restrict__ bgate) {
  const int h = blockIdx.x;
  const int tid = threadIdx.x;
  const int lane = tid & 63;
  __shared__ int cnt[8];
  if (tid < 8) cnt[tid] = 0;
  __syncthreads();
  for (int chunk = 0; chunk < 16; ++chunk) {
    int t = chunk * 256 + tid;
    int2 e = Tvi[t * 8 + h];
    float2 g = Tvg[t * 8 + h];
#pragma unroll
    for (int role = 0; role < 2; ++role) {
      int mye = role ? e.y : e.x;
      float myg = role ? g.y : g.x;
      u16 entry = role ? (u16)(t | 0x8000) : (u16)t;
#pragma unroll
      for (int ee = 0; ee < 8; ++ee) {
        unsigned long long mask = __ballot(mye == ee);
        if (mye == ee) {
          int prefix = __popcll(mask & ((1ull << lane) - 1ull));
          int leader = __ffsll((unsigned long long)mask) - 1;
          int base = 0;
          if (lane == leader) base = atomicAdd(&cnt[ee], (int)__popcll(mask));
          base = __shfl(base, leader);
          int pos = base + prefix;
          btok[(h * 8 + ee) * 4096 + pos] = entry;
          bgate[(h * 8 + ee) * 4096 + pos] = myg;
        }
      }
    }
  }
  __syncthreads();
  if (tid < 8) bcnt[h * 8 + tid] = cnt[tid];
}

// ---------------- Q/K projection GEMM: 64x128 tile, dbuf prefetch + swizzle ----------------
// grid (64 tb, 8 nb, 2 qk)
__global__ __launch_bounds__(256) void gemm_qk(
    const u16* __restrict__ Xb, const u16* __restrict__ Wq, const u16* __restrict__ Wk,
    u16* __restrict__ Qo, u16* __restrict__ Ko) {
  __shared__ u16 Ash0[64 * 32], Ash1[64 * 32];
  __shared__ u16 Bsh0[128 * 32], Bsh1[128 * 32];
  const int tb = blockIdx.x, nb = blockIdx.y;
  const u16* W = blockIdx.z ? Wk : Wq;
  u16* Out = blockIdx.z ? Ko : Qo;
  const int tid = threadIdx.x;
  const int wave = tid >> 6, lane = tid & 63;
  const int lg = lane >> 4, lr = lane & 15;
  const int r0 = tid >> 2, r1 = (tid + 256) >> 2;
  const int c0 = swzcol(tid), c1 = swzcol(tid + 256);
  const size_t aw  = (size_t)(tb * 64 + r0) * 1024 + c0;
  const size_t bw0 = (size_t)(nb * 128 + r0) * 1024 + c0;
  const size_t bw1 = (size_t)(nb * 128 + r1) * 1024 + c1;
  const int csl = (lg ^ ((lr + (lr >> 2)) & 3)) << 3;
  f4v acc[4][2] = {};
#define STG_QK(A, B, k0) do { \
    glds16(&Xb[aw + (k0)], &A[tid * 8]); \
    glds16(&W[bw0 + (k0)], &B[tid * 8]); \
    glds16(&W[bw1 + (k0)], &B[(tid + 256) * 8]); \
  } while (0)
#define CMP_QK(A, B) do { \
    s8v af[4], bfr[2]; \
    _Pragma("unroll") for (int m = 0; m < 4; ++m) af[m] = *(const s8v*)&A[(m * 16 + lr) * 32 + csl]; \
    _Pragma("unroll") for (int n = 0; n < 2; ++n) bfr[n] = *(const s8v*)&B[(wave * 32 + n * 16 + lr) * 32 + csl]; \
    _Pragma("unroll") for (int m = 0; m < 4; ++m) \
      _Pragma("unroll") for (int n = 0; n < 2; ++n) \
        acc[m][n] = __builtin_amdgcn_mfma_f32_16x16x32_bf16(af[m], bfr[n], acc[m][n], 0, 0, 0); \
  } while (0)
  STG_QK(Ash0, Bsh0, 0);
  for (int kt = 0; kt < 32; kt += 2) {
    WAITB();
    if (kt + 1 < 32) STG_QK(Ash1, Bsh1, (kt + 1) * 32);
    CMP_QK(Ash0, Bsh0);
    WAITB();
    if (kt + 2 < 32) STG_QK(Ash0, Bsh0, (kt + 2) * 32);
    CMP_QK(Ash1, Bsh1);
  }
#undef STG_QK
#undef CMP_QK
#pragma unroll
  for (int m = 0; m < 4; ++m) {
    int tbase = tb * 64 + m * 16 + lg * 4;
    int b = tbase >> 11, s = tbase & 2047;
#pragma unroll
    for (int n = 0; n < 2; ++n) {
      int p = wave * 32 + n * 16 + lr;
      size_t base = ((size_t)(b * 8 + nb) * 2048 + s) * 128 + p;
#pragma unroll
      for (int j = 0; j < 4; ++j)
        Out[base + (size_t)j * 128] = bf16_rne(acc[m][n][j]);
    }
  }
}

// ---------------- V expert GEMM v3: per-(h,e) buckets, 128x128 tile, role-split partials ----------------
// grid (32 tiles, 64 buckets) with XCD-aware remap: XCD k owns buckets 8k..8k+7 (B panels L2-resident).
__global__ __launch_bounds__(256) void gemm_v_e(
    const u16* __restrict__ Xb, const u16* __restrict__ Vw /*[h][p][e][d]*/,
    const int* __restrict__ bcnt, const u16* __restrict__ btok,
    const float* __restrict__ bgate, u16* __restrict__ VpA, u16* __restrict__ VpB) {
  const int id = blockIdx.x + 32 * blockIdx.y;
  const int xk = id & 7, j = id >> 3;          // j in 0..255
  const int bucket = 8 * xk + (j & 7);
  const int tile = j >> 3;                     // 0..31
  const int h = bucket >> 3, e = bucket & 7;
  const int cnt = bcnt[bucket];
  if (tile * 128 >= cnt) return;
  __shared__ u16 Ash0[128 * 32], Ash1[128 * 32];
  __shared__ u16 Bsh0[128 * 32], Bsh1[128 * 32];
  __shared__ int toksh[128];
  __shared__ float gsh[128];
  const int tid = threadIdx.x;
  if (tid < 128) {
    int ar = tile * 128 + tid;
    if (ar < cnt) {
      toksh[tid] = btok[bucket * 4096 + ar];
      gsh[tid] = bgate[bucket * 4096 + ar];
    } else { toksh[tid] = 0; gsh[tid] = 0.f; }
  }
  __syncthreads();
  const int wave = tid >> 6, lane = tid & 63;
  const int wm = wave >> 1, wn = wave & 1;
  const int lg = lane >> 4, lr = lane & 15;
  const int r0 = tid >> 2, r1 = (tid + 256) >> 2;
  const int c0 = swzcol(tid), c1 = swzcol(tid + 256);
  const size_t aw0 = (size_t)(toksh[r0] & 0xFFF) * 1024 + c0;
  const size_t aw1 = (size_t)(toksh[r1] & 0xFFF) * 1024 + c1;
  const size_t bw0 = ((size_t)(h * 128 + r0) * 8 + e) * 1024 + c0;
  const size_t bw1 = ((size_t)(h * 128 + r1) * 8 + e) * 1024 + c1;
  const int csl = (lg ^ ((lr + (lr >> 2)) & 3)) << 3;
  f4v acc[4][4] = {};
#define STG_VE(A, B, k0) do { \
    glds16(&Xb[aw0 + (k0)], &A[tid * 8]); \
    glds16(&Xb[aw1 + (k0)], &A[(tid + 256) * 8]); \
    glds16(&Vw[bw0 + (k0)], &B[tid * 8]); \
    glds16(&Vw[bw1 + (k0)], &B[(tid + 256) * 8]); \
  } while (0)
#define CMP_VE(A, B) do { \
    s8v af[4], bfr[4]; \
    _Pragma("unroll") for (int m = 0; m < 4; ++m) af[m] = *(const s8v*)&A[(wm * 64 + m * 16 + lr) * 32 + csl]; \
    _Pragma("unroll") for (int n = 0; n < 4; ++n) bfr[n] = *(const s8v*)&B[(wn * 64 + n * 16 + lr) * 32 + csl]; \
    _Pragma("unroll") for (int m = 0; m < 4; ++m) \
      _Pragma("unroll") for (int n = 0; n < 4; ++n) \
        acc[m][n] = __builtin_amdgcn_mfma_f32_16x16x32_bf16(af[m], bfr[n], acc[m][n], 0, 0, 0); \
  } while (0)
  STG_VE(Ash0, Bsh0, 0);
  for (int kt = 0; kt < 32; kt += 2) {
    WAITB();
    if (kt + 1 < 32) STG_VE(Ash1, Bsh1, (kt + 1) * 32);
    CMP_VE(Ash0, Bsh0);
    WAITB();
    if (kt + 2 < 32) STG_VE(Ash0, Bsh0, (kt + 2) * 32);
    CMP_VE(Ash1, Bsh1);
  }
#undef STG_VE
#undef CMP_VE
#pragma unroll
  for (int m = 0; m < 4; ++m) {
#pragma unroll
    for (int j2 = 0; j2 < 4; ++j2) {
      int row = wm * 64 + m * 16 + lg * 4 + j2;
      int ar = tile * 128 + row;
      if (ar < cnt) {
        int entry = toksh[row];
        int tok = entry & 0xFFF;
        u16* dst = (entry & 0x8000) ? VpB : VpA;
        float g = gsh[row];
#pragma unroll
        for (int n = 0; n < 4; ++n) {
          int p = wn * 64 + n * 16 + lr;
          dst[(size_t)tok * 1024 + h * 128 + p] = bf16_rne(g * acc[m][n][j2]);
        }
      }
    }
  }
}

// ---------------- vadd_transpose: VT[bh][p][s] = VpA[t][hp] + VpB[t][hp] ----------------
__global__ void vadd_transpose(const u16* __restrict__ VpA, const u16* __restrict__ VpB,
                               u16* __restrict__ VT) {
  __shared__ u16 tile[64][136];
  const int sb = blockIdx.x, bh = blockIdx.y;
  const int b = bh >> 3, h = bh & 7;
  const int tid = threadIdx.x;
#pragma unroll
  for (int it = 0; it < 4; ++it) {
    int idx = tid + it * 256;
    int r = idx >> 4, c8 = (idx & 15) << 3;
    size_t off = (size_t)(b * 2048 + sb * 64 + r) * 1024 + h * 128 + c8;
    s8v va = *(const s8v*)&VpA[off];
    s8v vb = *(const s8v*)&VpB[off];
    s8v o;
#pragma unroll
    for (int j = 0; j < 8; ++j) o[j] = (short)bf16_rne(bf2f((u16)va[j]) + bf2f((u16)vb[j]));
    *(s8v*)&tile[r][c8] = o;
  }
  __syncthreads();
#pragma unroll
  for (int it = 0; it < 8; ++it) {
    int idx = tid + it * 256;
    int p = idx >> 4, c4 = (idx & 15) << 2;
    us4 o;
#pragma unroll
    for (int j = 0; j < 4; ++j) o[j] = tile[c4 + j][p];
    *(us4*)&VT[((size_t)bh * 128 + p) * 2048 + sb * 64 + c4] = o;
  }
}

// ---------------- attention (flash-style), XCD-aware remap + setprio ----------------
// 512 blocks: XCD k owns bh {2k, 2k+1} -> K/V working set 2MB, L2-resident per XCD.
__global__ __launch_bounds__(256, 2) void attn(
    const u16* __restrict__ Q, const u16* __restrict__ K,
    const u16* __restrict__ VT, u16* __restrict__ CTX) {
  __shared__ u16 Kt[64 * 136];
  __shared__ u16 Vt[128 * 72];
  __shared__ u16 Pl[4][16 * 72];
  const int id = blockIdx.x + 32 * blockIdx.y;
  const int xk = id & 7, j = id >> 3;          // j in 0..63
  const int bh = 2 * xk + (j >> 5);
  const int qb = j & 31;
  const int tid = threadIdx.x;
  const int wave = tid >> 6, lane = tid & 63;
  const int lg = lane >> 4, lr = lane & 15;
  const size_t base = (size_t)bh * 2048 * 128;
  const int q0 = qb * 64 + wave * 16;
  s8v qf[4];
#pragma unroll
  for (int ks = 0; ks < 4; ++ks)
    qf[ks] = *(const s8v*)&Q[base + (size_t)(q0 + lr) * 128 + ks * 32 + lg * 8];
  f4v cacc[8] = {};
  float mrun = -1e30f, ssum = 0.f;
  for (int kb = 0; kb < 32; ++kb) {
    __syncthreads();
#pragma unroll
    for (int i = 0; i < 4; ++i) {
      int idx = tid + i * 256;
      int r = idx >> 4, c8 = (idx & 15) << 3;
      *(s8v*)&Kt[r * 136 + c8] = *(const s8v*)&K[base + (size_t)(kb * 64 + r) * 128 + c8];
    }
#pragma unroll
    for (int i = 0; i < 4; ++i) {
      int idx = tid + i * 256;
      int r = idx >> 3, c8 = (idx & 7) << 3;
      *(s8v*)&Vt[r * 72 + c8] = *(const s8v*)&VT[base + (size_t)r * 2048 + kb * 64 + c8];
    }
    __syncthreads();
    f4v sc[4] = {};
    __builtin_amdgcn_s_setprio(1);
#pragma unroll
    for (int ks = 0; ks < 4; ++ks) {
#pragma unroll
      for (int m = 0; m < 4; ++m) {
        s8v ak = *(const s8v*)&Kt[(m * 16 + lr) * 136 + ks * 32 + lg * 8];
        sc[m] = __builtin_amdgcn_mfma_f32_16x16x32_bf16(ak, qf[ks], sc[m], 0, 0, 0);
      }
    }
    __builtin_amdgcn_s_setprio(0);
    float tmax = -1e30f;
#pragma unroll
    for (int m = 0; m < 4; ++m)
#pragma unroll
      for (int j2 = 0; j2 < 4; ++j2) {
        float v = sc[m][j2] * ATT_SCALE;
        sc[m][j2] = v;
        tmax = fmaxf(tmax, v);
      }
    tmax = fmaxf(tmax, __shfl_xor(tmax, 16));
    tmax = fmaxf(tmax, __shfl_xor(tmax, 32));
    float mnew = fmaxf(mrun, tmax);
    float f = __expf(mrun - mnew);
    mrun = mnew;
    float psum = 0.f;
#pragma unroll
    for (int m = 0; m < 4; ++m) {
      us4 pk;
#pragma unroll
      for (int j2 = 0; j2 < 4; ++j2) {
        float pe = __expf(sc[m][j2] - mnew);
        psum += pe;
        pk[j2] = bf16_rne(pe);
      }
      *(us4*)&Pl[wave][lr * 72 + m * 16 + lg * 4] = pk;
    }
    psum += __shfl_xor(psum, 16);
    psum += __shfl_xor(psum, 32);
    ssum = ssum * f + psum;
#pragma unroll
    for (int mr = 0; mr < 8; ++mr)
#pragma unroll
      for (int j2 = 0; j2 < 4; ++j2) cacc[mr][j2] *= f;
    __builtin_amdgcn_s_setprio(1);
#pragma unroll
    for (int ks = 0; ks < 2; ++ks) {
      s8v bp = *(const s8v*)&Pl[wave][lr * 72 + ks * 32 + lg * 8];
#pragma unroll
      for (int mr = 0; mr < 8; ++mr) {
        s8v av = *(const s8v*)&Vt[(mr * 16 + lr) * 72 + ks * 32 + lg * 8];
        cacc[mr] = __builtin_amdgcn_mfma_f32_16x16x32_bf16(av, bp, cacc[mr], 0, 0, 0);
      }
    }
    __builtin_amdgcn_s_setprio(0);
  }
  float rinv = 1.f / ssum;
#pragma unroll
  for (int mr = 0; mr < 8; ++mr) {
    us4 pk;
#pragma unroll
    for (int j2 = 0; j2 < 4; ++j2) pk[j2] = bf16_rne(cacc[mr][j2] * rinv);
    *(us4*)&CTX[base + (size_t)(q0 + lr) * 128 + mr * 16 + lg * 4] = pk;
  }
}

// ---------------- pregate: CTXG[t][he*128+p] = gate_o[t,he] * ctx[t,h,p] ----------------
__global__ __launch_bounds__(256) void pregate(
    const u16* __restrict__ CTX, const int2* __restrict__ Toi, const float2* __restrict__ Tog,
    u16* __restrict__ CTXG) {
  const int t = blockIdx.x;
  const int tid = threadIdx.x;
  __shared__ float gsh[64];
  if (tid < 64) {
    int h = tid >> 3, e = tid & 7;
    int2 ei = Toi[t * 8 + h];
    float2 gg = Tog[t * 8 + h];
    gsh[tid] = (e == ei.x) ? gg.x : ((e == ei.y) ? gg.y : 0.f);
  }
  __syncthreads();
  const int b = t >> 11, s = t & 2047;
#pragma unroll
  for (int c = 0; c < 4; ++c) {
    int chunk = tid + c * 256;            // 0..1023 chunks of 8 elems
    int he = chunk >> 4, p8 = (chunk & 15) << 3;
    int h = he >> 3;
    float g = gsh[he];
    s8v o;
    if (g != 0.f) {
      s8v v = *(const s8v*)&CTX[((size_t)(b * 8 + h) * 2048 + s) * 128 + p8];
#pragma unroll
      for (int j = 0; j < 8; ++j) o[j] = (short)bf16_rne(bf2f((u16)v[j]) * g);
    } else {
#pragma unroll
      for (int j = 0; j < 8; ++j) o[j] = 0;
    }
    *(s8v*)&CTXG[(size_t)t * 8192 + chunk * 8] = o;
  }
}

// ---------------- O projection: dense 128^2, dbuf prefetch + swizzle, split-K=2 ----------------
// grid (32 tb, 8 db, 2 kz), NATURAL order (R10 XCD remap reverted: 3x FETCH regression).
__global__ __launch_bounds__(256) void gemm_o_dense(
    const u16* __restrict__ CTXG, const u16* __restrict__ Ow /*[d][8192]*/,
    float* __restrict__ OUT, float* __restrict__ OP1a, float* __restrict__ OP1b) {
  __shared__ u16 Ash0[128 * 32], Ash1[128 * 32];
  __shared__ u16 Bsh0[128 * 32], Bsh1[128 * 32];
  const int tb = blockIdx.x, db = blockIdx.y, kz = blockIdx.z;
  const int tid = threadIdx.x;
  const int wave = tid >> 6, lane = tid & 63;
  const int wm = wave >> 1, wn = wave & 1;
  const int lg = lane >> 4, lr = lane & 15;
  const size_t kbase = (size_t)kz * 4096;
  const int r0 = tid >> 2, r1 = (tid + 256) >> 2;
  const int c0 = swzcol(tid), c1 = swzcol(tid + 256);
  const size_t aw0 = (size_t)(tb * 128 + r0) * 8192 + kbase + c0;
  const size_t aw1 = (size_t)(tb * 128 + r1) * 8192 + kbase + c1;
  const size_t bw0 = (size_t)(db * 128 + r0) * 8192 + kbase + c0;
  const size_t bw1 = (size_t)(db * 128 + r1) * 8192 + kbase + c1;
  const int csl = (lg ^ ((lr + (lr >> 2)) & 3)) << 3;
  f4v acc[4][4] = {};
#define STG_O(A, B, k0) do { \
    glds16(&CTXG[aw0 + (k0)], &A[tid * 8]); \
    glds16(&CTXG[aw1 + (k0)], &A[(tid + 256) * 8]); \
    glds16(&Ow[bw0 + (k0)], &B[tid * 8]); \
    glds16(&Ow[bw1 + (k0)], &B[(tid + 256) * 8]); \
  } while (0)
#define CMP_O(A, B) do { \
    s8v af[4], bfr[4]; \
    _Pragma("unroll") for (int m = 0; m < 4; ++m) af[m] = *(const s8v*)&A[(wm * 64 + m * 16 + lr) * 32 + csl]; \
    _Pragma("unroll") for (int n = 0; n < 4; ++n) bfr[n] = *(const s8v*)&B[(wn * 64 + n * 16 + lr) * 32 + csl]; \
    _Pragma("unroll") for (int m = 0; m < 4; ++m) \
      _Pragma("unroll") for (int n = 0; n < 4; ++n) \
        acc[m][n] = __builtin_amdgcn_mfma_f32_16x16x32_bf16(af[m], bfr[n], acc[m][n], 0, 0, 0); \
  } while (0)
  STG_O(Ash0, Bsh0, 0);
  for (int kt = 0; kt < 128; kt += 2) {
    WAITB();
    if (kt + 1 < 128) STG_O(Ash1, Bsh1, (kt + 1) * 32);
    CMP_O(Ash0, Bsh0);
    WAITB();
    if (kt + 2 < 128) STG_O(Ash0, Bsh0, (kt + 2) * 32);
    CMP_O(Ash1, Bsh1);
  }
#undef STG_O
#undef CMP_O
  float* OP;
  if (kz == 0) OP = OUT;
  else OP = (tb < 16) ? OP1a : OP1b;
  const int toff = (kz == 0) ? tb * 128 : (tb & 15) * 128;
#pragma unroll
  for (int m = 0; m < 4; ++m) {
    int t = toff + wm * 64 + m * 16 + lg * 4;
#pragma unroll
    for (int n = 0; n < 4; ++n) {
      int d = db * 128 + wn * 64 + n * 16 + lr;
#pragma unroll
      for (int j2 = 0; j2 < 4; ++j2)
        OP[(size_t)(t + j2) * 1024 + d] = acc[m][n][j2];
    }
  }
}

// ---------------- OUT += partial (split halves) ----------------
__global__ void add_inplace(float* __restrict__ OUT, const float* __restrict__ P0,
                            const float* __restrict__ P1) {
  size_t i = ((size_t)blockIdx.x * 256 + threadIdx.x) * 4;  // 4M floats
  const float* P = (i < 2097152) ? (P0 + i) : (P1 + (i - 2097152));
  float4 a = *(const float4*)&OUT[i];
  float4 b = *(const float4*)P;
  *(float4*)&OUT[i] = make_float4(a.x + b.x, a.y + b.y, a.z + b.z, a.w + b.w);
}

extern "C" void kernel_launch(void* const* d_in, const int* in_sizes, int n_in,
                              void* d_out, int out_size, void* d_ws, size_t ws_size,
                              hipStream_t stream) {
  const float* x     = (const float*)d_in[0];
  const float* q_w   = (const float*)d_in[1];
  const float* k_w   = (const float*)d_in[2];
  const float* v_w   = (const float*)d_in[3];
  const float* o_w   = (const float*)d_in[4];
  const float* sel_v = (const float*)d_in[5];
  const float* sel_o = (const float*)d_in[6];
  const float* rs    = (const float*)d_in[7];

  char* ws = (char*)d_ws;
  const size_t MB = 1048576;
  const size_t KB = 1024;
  // Timeline / overlays (96 MB peak, proven ws >= 97.5 MB):
  u16*    xb    = (u16*)(ws);                        // [0,8M): xb -> ctx -> op1a
  u16*    ctx   = (u16*)(ws);
  float*  op1a  = (float*)(ws);
  u16*    qwb   = (u16*)(ws + 8 * MB);               // [8,10M) dead after gemm_qk
  u16*    kwb   = (u16*)(ws + 10 * MB);              // [10,12M)
  u16*    ctxg  = (u16*)(ws + 8 * MB);               // [8,72M) from pregate on
  u16*    vwT   = (u16*)(ws + 12 * MB);              // [12,28M) dead after gemm_v_e
  u16*    vt    = (u16*)(ws + 12 * MB);              // [12,20M) written after vwT dead
  u16*    vpA   = (u16*)(ws + 28 * MB);              // [28,36M) role-0 partials
  u16*    vpB   = (u16*)(ws + 36 * MB);              // [36,44M) role-1 partials
  u16*    qh    = (u16*)(ws + 49 * MB + 512 * KB);   // [49.5,57.5M)
  u16*    kh    = (u16*)(ws + 57 * MB + 512 * KB);   // [57.5,65.5M)
  int2*   tvi   = (int2*)(ws + 72 * MB);             // [72,80M): routing/bucket meta -> op1b
  float2* tvg   = (float2*)(ws + 72 * MB + 256 * KB);
  int2*   toi   = (int2*)(ws + 72 * MB + 512 * KB);
  float2* tog   = (float2*)(ws + 72 * MB + 768 * KB);
  int*    bcnt2 = (int*)(ws + 73 * MB);              // 256B (pad to 4K)
  u16*    btok2 = (u16*)(ws + 73 * MB + 4 * KB);     // 512K
  float*  bgate2= (float*)(ws + 73 * MB + 520 * KB); // 1M -> ends 73M+1544K
  float*  op1b  = (float*)(ws + 72 * MB);
  u16*    owT   = (u16*)(ws + 80 * MB);              // [80,96M) live until gemm_o_dense
  float*  outp  = (float*)d_out;

  hipLaunchKernelGGL(conv_qk, dim3(2048), dim3(256), 0, stream, q_w, k_w, qwb, kwb);
  hipLaunchKernelGGL(transpose_w, dim3(4, 32, 64), dim3(256), 0, stream, v_w, vwT, 0);
  hipLaunchKernelGGL(transpose_w, dim3(32, 4, 64), dim3(256), 0, stream, o_w, owT, 1);
  hipLaunchKernelGGL(routing, dim3(512), dim3(256), 0, stream, x, sel_v, sel_o, rs, tvi, tvg, toi, tog, xb);
  hipLaunchKernelGGL(build_buckets2, dim3(8), dim3(256), 0, stream, tvi, tvg, bcnt2, btok2, bgate2);
  hipLaunchKernelGGL(gemm_v_e, dim3(32, 64), dim3(256), 0, stream, xb, vwT, bcnt2, btok2, bgate2, vpA, vpB);
  hipLaunchKernelGGL(vadd_transpose, dim3(32, 16), dim3(256), 0, stream, vpA, vpB, vt);
  hipLaunchKernelGGL(gemm_qk, dim3(64, 8, 2), dim3(256), 0, stream, xb, qwb, kwb, qh, kh);
  hipLaunchKernelGGL(attn, dim3(32, 16), dim3(256), 0, stream, qh, kh, vt, ctx);
  hipLaunchKernelGGL(pregate, dim3(4096), dim3(256), 0, stream, ctx, toi, tog, ctxg);
  hipLaunchKernelGGL(gemm_o_dense, dim3(32, 8, 2), dim3(256), 0, stream, ctxg, owT, outp, op1a, op1b);
  hipLaunchKernelGGL(add_inplace, dim3(4096), dim3(256), 0, stream, outp, op1a, op1b);
}

// Round 12
// 367.523 us; speedup vs baseline: 1.7563x; 1.0012x over previous
//
#include <hip/hip_runtime.h>

// SwitchHeadCore: B=2,S=2048,D=1024,H=8,E=8,P=128,K=2(top-k). T = 4096.

typedef unsigned short u16;
typedef __attribute__((ext_vector_type(8))) short s8v;   // 8 x bf16 (MFMA A/B frag)
typedef __attribute__((ext_vector_type(4))) float f4v;   // MFMA C/D frag
typedef __attribute__((ext_vector_type(4))) unsigned short us4;

#define ATT_SCALE 0.08838834764831845f

__device__ inline u16 bf16_rne(float f) {
  union { float f; unsigned u; } v; v.f = f;
  unsigned r = v.u + 0x7fffu + ((v.u >> 16) & 1u);
  return (u16)(r >> 16);
}
__device__ inline float bf2f(u16 h) {
  union { unsigned u; float f; } v; v.u = ((unsigned)h) << 16;
  return v.f;
}

// async global->LDS, 16B per lane. Global src may be per-lane; LDS dest linear in lane order.
__device__ inline void glds16(const void* g, void* l) {
  __builtin_amdgcn_global_load_lds((const __attribute__((address_space(1))) void*)g,
                                   (__attribute__((address_space(3))) void*)l, 16, 0, 0);
}
// swizzled source column (u16 units) for staging lane index idx (rows of 32 u16, 4 slots of 8)
__device__ inline int swzcol(int idx) {
  int r = idx >> 2;
  return (((idx & 3) ^ ((r + (r >> 2)) & 3)) << 3);
}
#define WAITB() do { asm volatile("s_waitcnt vmcnt(0)" ::: "memory"); __syncthreads(); } while (0)

// ---------------- weight prep ----------------
__global__ void conv_qk(const float* __restrict__ Q, const float* __restrict__ K,
                        u16* __restrict__ Qb, u16* __restrict__ Kb) {
  int i = blockIdx.x * 256 + threadIdx.x;
  const float* src; u16* dst; int off;
  if (i < 262144) { src = Q; dst = Qb; off = i; }
  else            { src = K; dst = Kb; off = i - 262144; }
  float4 v = *(const float4*)&src[(size_t)off * 4];
  us4 o; o[0]=bf16_rne(v.x); o[1]=bf16_rne(v.y); o[2]=bf16_rne(v.z); o[3]=bf16_rne(v.w);
  *(us4*)&dst[(size_t)off * 4] = o;
}

// mode 0: v_w [he][1024 d][128 p] -> vwT [h][p][e][d]
// mode 1: o_w [he][128 p][1024 d] -> owT [d][he*128+p]
__global__ void transpose_w(const float* __restrict__ src, u16* __restrict__ dst, int mode) {
  __shared__ float tile[32][33];
  int he = blockIdx.z;
  int C = mode ? 1024 : 128;
  int r0 = blockIdx.y * 32, c0 = blockIdx.x * 32;
  int lc = threadIdx.x & 31, rr = threadIdx.x >> 5;
  const float* s = src + (size_t)he * 131072;
#pragma unroll
  for (int i = 0; i < 4; ++i) {
    int r = rr + i * 8;
    tile[r][lc] = s[(size_t)(r0 + r) * C + c0 + lc];
  }
  __syncthreads();
#pragma unroll
  for (int i = 0; i < 4; ++i) {
    int c = rr + i * 8;
    float v = tile[lc][c];
    size_t a;
    if (mode) a = (size_t)(c0 + c) * 8192 + (size_t)he * 128 + (r0 + lc);
    else      a = (size_t)(he >> 3) * 1048576 + (size_t)(c0 + c) * 8192 + (size_t)(he & 7) * 1024 + (r0 + lc);
    dst[a] = bf16_rne(v);
  }
}

// ---------------- routing + x->bf16 ----------------
__global__ __launch_bounds__(256, 2) void routing(
    const float* __restrict__ X, const float* __restrict__ SelV, const float* __restrict__ SelO,
    const float* __restrict__ RS, int2* __restrict__ Tvi, float2* __restrict__ Tvg,
    int2* __restrict__ Toi, float2* __restrict__ Tog, u16* __restrict__ Xb) {
  __shared__ float xs[8][1024];
  __shared__ float lgs[8][128];
  int t0 = blockIdx.x * 8;
  int tid = threadIdx.x;
  for (int i = tid; i < 2048; i += 256) {
    int row = i >> 8, c = (i & 255) * 4;
    float4 v = *(const float4*)&X[(size_t)(t0 + row) * 1024 + c];
    *(float4*)&xs[row][c] = v;
    us4 o; o[0]=bf16_rne(v.x); o[1]=bf16_rne(v.y); o[2]=bf16_rne(v.z); o[3]=bf16_rne(v.w);
    *(us4*)&Xb[(size_t)(t0 + row) * 1024 + c] = o;
  }
  __syncthreads();
  {
    int widx = tid & 127, tg = tid >> 7;
    const float* w = (widx < 64) ? (SelV + (size_t)widx * 1024) : (SelO + (size_t)(widx - 64) * 1024);
    float acc[4] = {0.f, 0.f, 0.f, 0.f};
    for (int k = 0; k < 1024; k += 4) {
      float4 wv = *(const float4*)&w[k];
#pragma unroll
      for (int t = 0; t < 4; ++t) {
        float4 xv = *(const float4*)&xs[tg * 4 + t][k];
        acc[t] += wv.x * xv.x + wv.y * xv.y + wv.z * xv.z + wv.w * xv.w;
      }
    }
#pragma unroll
    for (int t = 0; t < 4; ++t) lgs[tg * 4 + t][widx] = acc[t];
  }
  __syncthreads();
  if (tid < 128) {
    float rs = RS[0];
    int tok = tid >> 4, which = (tid >> 3) & 1, h = tid & 7;
    float p[8];
#pragma unroll
    for (int e = 0; e < 8; ++e)
      p[e] = 1.f / (1.f + __expf(-lgs[tok][which * 64 + h * 8 + e]));
    float v1 = -1.f; int i1 = -1;
#pragma unroll
    for (int e = 0; e < 8; ++e) if (p[e] > v1) { v1 = p[e]; i1 = e; }
    float v2 = -1.f; int i2 = -1;
#pragma unroll
    for (int e = 0; e < 8; ++e) if (e != i1 && p[e] > v2) { v2 = p[e]; i2 = e; }
    float ssum = fmaxf(v1 + v2, 1e-9f);
    float g1 = v1 / ssum * rs, g2 = v2 / ssum * rs;
    int t = t0 + tok;
    int lo, hi; float glo, ghi;
    if (i1 < i2) { lo = i1; hi = i2; glo = g1; ghi = g2; }
    else         { lo = i2; hi = i1; glo = g2; ghi = g1; }
    if (which) { Toi[t * 8 + h] = make_int2(lo, hi); Tog[t * 8 + h] = make_float2(glo, ghi); }
    else       { Tvi[t * 8 + h] = make_int2(lo, hi); Tvg[t * 8 + h] = make_float2(glo, ghi); }
  }
}

// ---------------- V bucket build v3: wave-aggregated, LDS counters, 1 block/head ----------------
__global__ __launch_bounds__(256) void build_buckets2(
    const int2* __restrict__ Tvi, const float2* __restrict__ Tvg,
    int* __restrict__ bcnt, u16* __restrict__ btok, float* __restrict__ bgate) {
  const int h = blockIdx.x;
  const int tid = threadIdx.x;
  const int lane = tid & 63;
  __shared__ int cnt[8];
  if (tid < 8) cnt[tid] = 0;
  __syncthreads();
  for (int chunk = 0; chunk < 16; ++chunk) {
    int t = chunk * 256 + tid;
    int2 e = Tvi[t * 8 + h];
    float2 g = Tvg[t * 8 + h];
#pragma unroll
    for (int role = 0; role < 2; ++role) {
      int mye = role ? e.y : e.x;
      float myg = role ? g.y : g.x;
      u16 entry = role ? (u16)(t | 0x8000) : (u16)t;
#pragma unroll
      for (int ee = 0; ee < 8; ++ee) {
        unsigned long long mask = __ballot(mye == ee);
        if (mye == ee) {
          int prefix = __popcll(mask & ((1ull << lane) - 1ull));
          int leader = __ffsll((unsigned long long)mask) - 1;
          int base = 0;
          if (lane == leader) base = atomicAdd(&cnt[ee], (int)__popcll(mask));
          base = __shfl(base, leader);
          int pos = base + prefix;
          btok[(h * 8 + ee) * 4096 + pos] = entry;
          bgate[(h * 8 + ee) * 4096 + pos] = myg;
        }
      }
    }
  }
  __syncthreads();
  if (tid < 8) bcnt[h * 8 + tid] = cnt[tid];
}

// ---------------- Q/K projection GEMM: 64x128 tile, dbuf prefetch + swizzle ----------------
// grid (64 tb, 8 nb, 2 qk)
__global__ __launch_bounds__(256) void gemm_qk(
    const u16* __restrict__ Xb, const u16* __restrict__ Wq, const u16* __restrict__ Wk,
    u16* __restrict__ Qo, u16* __restrict__ Ko) {
  __shared__ u16 Ash0[64 * 32], Ash1[64 * 32];
  __shared__ u16 Bsh0[128 * 32], Bsh1[128 * 32];
  const int tb = blockIdx.x, nb = blockIdx.y;
  const u16* W = blockIdx.z ? Wk : Wq;
  u16* Out = blockIdx.z ? Ko : Qo;
  const int tid = threadIdx.x;
  const int wave = tid >> 6, lane = tid & 63;
  const int lg = lane >> 4, lr = lane & 15;
  const int r0 = tid >> 2, r1 = (tid + 256) >> 2;
  const int c0 = swzcol(tid), c1 = swzcol(tid + 256);
  const size_t aw  = (size_t)(tb * 64 + r0) * 1024 + c0;
  const size_t bw0 = (size_t)(nb * 128 + r0) * 1024 + c0;
  const size_t bw1 = (size_t)(nb * 128 + r1) * 1024 + c1;
  const int csl = (lg ^ ((lr + (lr >> 2)) & 3)) << 3;
  f4v acc[4][2] = {};
#define STG_QK(A, B, k0) do { \
    glds16(&Xb[aw + (k0)], &A[tid * 8]); \
    glds16(&W[bw0 + (k0)], &B[tid * 8]); \
    glds16(&W[bw1 + (k0)], &B[(tid + 256) * 8]); \
  } while (0)
#define CMP_QK(A, B) do { \
    s8v af[4], bfr[2]; \
    _Pragma("unroll") for (int m = 0; m < 4; ++m) af[m] = *(const s8v*)&A[(m * 16 + lr) * 32 + csl]; \
    _Pragma("unroll") for (int n = 0; n < 2; ++n) bfr[n] = *(const s8v*)&B[(wave * 32 + n * 16 + lr) * 32 + csl]; \
    _Pragma("unroll") for (int m = 0; m < 4; ++m) \
      _Pragma("unroll") for (int n = 0; n < 2; ++n) \
        acc[m][n] = __builtin_amdgcn_mfma_f32_16x16x32_bf16(af[m], bfr[n], acc[m][n], 0, 0, 0); \
  } while (0)
  STG_QK(Ash0, Bsh0, 0);
  for (int kt = 0; kt < 32; kt += 2) {
    WAITB();
    if (kt + 1 < 32) STG_QK(Ash1, Bsh1, (kt + 1) * 32);
    CMP_QK(Ash0, Bsh0);
    WAITB();
    if (kt + 2 < 32) STG_QK(Ash0, Bsh0, (kt + 2) * 32);
    CMP_QK(Ash1, Bsh1);
  }
#undef STG_QK
#undef CMP_QK
#pragma unroll
  for (int m = 0; m < 4; ++m) {
    int tbase = tb * 64 + m * 16 + lg * 4;
    int b = tbase >> 11, s = tbase & 2047;
#pragma unroll
    for (int n = 0; n < 2; ++n) {
      int p = wave * 32 + n * 16 + lr;
      size_t base = ((size_t)(b * 8 + nb) * 2048 + s) * 128 + p;
#pragma unroll
      for (int j = 0; j < 4; ++j)
        Out[base + (size_t)j * 128] = bf16_rne(acc[m][n][j]);
    }
  }
}

// ---------------- V expert GEMM v3: per-(h,e) buckets, 128x128 tile, role-split partials ----------------
// grid (32 tiles, 64 buckets) with XCD-aware remap: XCD k owns buckets 8k..8k+7 (B panels L2-resident).
__global__ __launch_bounds__(256) void gemm_v_e(
    const u16* __restrict__ Xb, const u16* __restrict__ Vw /*[h][p][e][d]*/,
    const int* __restrict__ bcnt, const u16* __restrict__ btok,
    const float* __restrict__ bgate, u16* __restrict__ VpA, u16* __restrict__ VpB) {
  const int id = blockIdx.x + 32 * blockIdx.y;
  const int xk = id & 7, j = id >> 3;          // j in 0..255
  const int bucket = 8 * xk + (j & 7);
  const int tile = j >> 3;                     // 0..31
  const int h = bucket >> 3, e = bucket & 7;
  const int cnt = bcnt[bucket];
  if (tile * 128 >= cnt) return;
  __shared__ u16 Ash0[128 * 32], Ash1[128 * 32];
  __shared__ u16 Bsh0[128 * 32], Bsh1[128 * 32];
  __shared__ int toksh[128];
  __shared__ float gsh[128];
  const int tid = threadIdx.x;
  if (tid < 128) {
    int ar = tile * 128 + tid;
    if (ar < cnt) {
      toksh[tid] = btok[bucket * 4096 + ar];
      gsh[tid] = bgate[bucket * 4096 + ar];
    } else { toksh[tid] = 0; gsh[tid] = 0.f; }
  }
  __syncthreads();
  const int wave = tid >> 6, lane = tid & 63;
  const int wm = wave >> 1, wn = wave & 1;
  const int lg = lane >> 4, lr = lane & 15;
  const int r0 = tid >> 2, r1 = (tid + 256) >> 2;
  const int c0 = swzcol(tid), c1 = swzcol(tid + 256);
  const size_t aw0 = (size_t)(toksh[r0] & 0xFFF) * 1024 + c0;
  const size_t aw1 = (size_t)(toksh[r1] & 0xFFF) * 1024 + c1;
  const size_t bw0 = ((size_t)(h * 128 + r0) * 8 + e) * 1024 + c0;
  const size_t bw1 = ((size_t)(h * 128 + r1) * 8 + e) * 1024 + c1;
  const int csl = (lg ^ ((lr + (lr >> 2)) & 3)) << 3;
  f4v acc[4][4] = {};
#define STG_VE(A, B, k0) do { \
    glds16(&Xb[aw0 + (k0)], &A[tid * 8]); \
    glds16(&Xb[aw1 + (k0)], &A[(tid + 256) * 8]); \
    glds16(&Vw[bw0 + (k0)], &B[tid * 8]); \
    glds16(&Vw[bw1 + (k0)], &B[(tid + 256) * 8]); \
  } while (0)
#define CMP_VE(A, B) do { \
    s8v af[4], bfr[4]; \
    _Pragma("unroll") for (int m = 0; m < 4; ++m) af[m] = *(const s8v*)&A[(wm * 64 + m * 16 + lr) * 32 + csl]; \
    _Pragma("unroll") for (int n = 0; n < 4; ++n) bfr[n] = *(const s8v*)&B[(wn * 64 + n * 16 + lr) * 32 + csl]; \
    _Pragma("unroll") for (int m = 0; m < 4; ++m) \
      _Pragma("unroll") for (int n = 0; n < 4; ++n) \
        acc[m][n] = __builtin_amdgcn_mfma_f32_16x16x32_bf16(af[m], bfr[n], acc[m][n], 0, 0, 0); \
  } while (0)
  STG_VE(Ash0, Bsh0, 0);
  for (int kt = 0; kt < 32; kt += 2) {
    WAITB();
    if (kt + 1 < 32) STG_VE(Ash1, Bsh1, (kt + 1) * 32);
    CMP_VE(Ash0, Bsh0);
    WAITB();
    if (kt + 2 < 32) STG_VE(Ash0, Bsh0, (kt + 2) * 32);
    CMP_VE(Ash1, Bsh1);
  }
#undef STG_VE
#undef CMP_VE
#pragma unroll
  for (int m = 0; m < 4; ++m) {
#pragma unroll
    for (int j2 = 0; j2 < 4; ++j2) {
      int row = wm * 64 + m * 16 + lg * 4 + j2;
      int ar = tile * 128 + row;
      if (ar < cnt) {
        int entry = toksh[row];
        int tok = entry & 0xFFF;
        u16* dst = (entry & 0x8000) ? VpB : VpA;
        float g = gsh[row];
#pragma unroll
        for (int n = 0; n < 4; ++n) {
          int p = wn * 64 + n * 16 + lr;
          dst[(size_t)tok * 1024 + h * 128 + p] = bf16_rne(g * acc[m][n][j2]);
        }
      }
    }
  }
}

// ---------------- vadd_transpose: VT[bh][p][s] = VpA[t][hp] + VpB[t][hp] ----------------
__global__ void vadd_transpose(const u16* __restrict__ VpA, const u16* __restrict__ VpB,
                               u16* __restrict__ VT) {
  __shared__ u16 tile[64][136];
  const int sb = blockIdx.x, bh = blockIdx.y;
  const int b = bh >> 3, h = bh & 7;
  const int tid = threadIdx.x;
#pragma unroll
  for (int it = 0; it < 4; ++it) {
    int idx = tid + it * 256;
    int r = idx >> 4, c8 = (idx & 15) << 3;
    size_t off = (size_t)(b * 2048 + sb * 64 + r) * 1024 + h * 128 + c8;
    s8v va = *(const s8v*)&VpA[off];
    s8v vb = *(const s8v*)&VpB[off];
    s8v o;
#pragma unroll
    for (int j = 0; j < 8; ++j) o[j] = (short)bf16_rne(bf2f((u16)va[j]) + bf2f((u16)vb[j]));
    *(s8v*)&tile[r][c8] = o;
  }
  __syncthreads();
#pragma unroll
  for (int it = 0; it < 8; ++it) {
    int idx = tid + it * 256;
    int p = idx >> 4, c4 = (idx & 15) << 2;
    us4 o;
#pragma unroll
    for (int j = 0; j < 4; ++j) o[j] = tile[c4 + j][p];
    *(us4*)&VT[((size_t)bh * 128 + p) * 2048 + sb * 64 + c4] = o;
  }
}

// ---------------- attention: XCD remap + setprio + T14 async-stage (load-early / write-late) ----------------
// 512 blocks: XCD k owns bh {2k, 2k+1}. K/V for tile kb+1 loaded to regs during compute of tile kb.
__global__ __launch_bounds__(256, 2) void attn(
    const u16* __restrict__ Q, const u16* __restrict__ K,
    const u16* __restrict__ VT, u16* __restrict__ CTX) {
  __shared__ u16 Kt[64 * 136];
  __shared__ u16 Vt[128 * 72];
  __shared__ u16 Pl[4][16 * 72];
  const int id = blockIdx.x + 32 * blockIdx.y;
  const int xk = id & 7, j = id >> 3;          // j in 0..63
  const int bh = 2 * xk + (j >> 5);
  const int qb = j & 31;
  const int tid = threadIdx.x;
  const int wave = tid >> 6, lane = tid & 63;
  const int lg = lane >> 4, lr = lane & 15;
  const size_t base = (size_t)bh * 2048 * 128;
  const int q0 = qb * 64 + wave * 16;
  s8v qf[4];
#pragma unroll
  for (int ks = 0; ks < 4; ++ks)
    qf[ks] = *(const s8v*)&Q[base + (size_t)(q0 + lr) * 128 + ks * 32 + lg * 8];
  s8v kr[4], vr[4];
#define LOADKV(kb) do { \
    _Pragma("unroll") for (int i = 0; i < 4; ++i) { \
      int idx = tid + i * 256; \
      kr[i] = *(const s8v*)&K[base + (size_t)((kb) * 64 + (idx >> 4)) * 128 + ((idx & 15) << 3)]; \
      vr[i] = *(const s8v*)&VT[base + (size_t)(idx >> 3) * 2048 + (kb) * 64 + ((idx & 7) << 3)]; \
    } } while (0)
#define WRITEKV() do { \
    _Pragma("unroll") for (int i = 0; i < 4; ++i) { \
      int idx = tid + i * 256; \
      *(s8v*)&Kt[(idx >> 4) * 136 + ((idx & 15) << 3)] = kr[i]; \
      *(s8v*)&Vt[(idx >> 3) * 72 + ((idx & 7) << 3)] = vr[i]; \
    } } while (0)
  f4v cacc[8] = {};
  float mrun = -1e30f, ssum = 0.f;
  LOADKV(0);
  for (int kb = 0; kb < 32; ++kb) {
    asm volatile("s_waitcnt vmcnt(0)" ::: "memory");  // next-tile regs valid
    __syncthreads();                                   // all waves done with LDS
    WRITEKV();
    __syncthreads();                                   // LDS tile visible
    if (kb + 1 < 32) LOADKV(kb + 1);                   // HBM latency hides under compute below
    f4v sc[4] = {};
    __builtin_amdgcn_s_setprio(1);
#pragma unroll
    for (int ks = 0; ks < 4; ++ks) {
#pragma unroll
      for (int m = 0; m < 4; ++m) {
        s8v ak = *(const s8v*)&Kt[(m * 16 + lr) * 136 + ks * 32 + lg * 8];
        sc[m] = __builtin_amdgcn_mfma_f32_16x16x32_bf16(ak, qf[ks], sc[m], 0, 0, 0);
      }
    }
    __builtin_amdgcn_s_setprio(0);
    float tmax = -1e30f;
#pragma unroll
    for (int m = 0; m < 4; ++m)
#pragma unroll
      for (int j2 = 0; j2 < 4; ++j2) {
        float v = sc[m][j2] * ATT_SCALE;
        sc[m][j2] = v;
        tmax = fmaxf(tmax, v);
      }
    tmax = fmaxf(tmax, __shfl_xor(tmax, 16));
    tmax = fmaxf(tmax, __shfl_xor(tmax, 32));
    float mnew = fmaxf(mrun, tmax);
    float f = __expf(mrun - mnew);
    mrun = mnew;
    float psum = 0.f;
#pragma unroll
    for (int m = 0; m < 4; ++m) {
      us4 pk;
#pragma unroll
      for (int j2 = 0; j2 < 4; ++j2) {
        float pe = __expf(sc[m][j2] - mnew);
        psum += pe;
        pk[j2] = bf16_rne(pe);
      }
      *(us4*)&Pl[wave][lr * 72 + m * 16 + lg * 4] = pk;
    }
    psum += __shfl_xor(psum, 16);
    psum += __shfl_xor(psum, 32);
    ssum = ssum * f + psum;
#pragma unroll
    for (int mr = 0; mr < 8; ++mr)
#pragma unroll
      for (int j2 = 0; j2 < 4; ++j2) cacc[mr][j2] *= f;
    __builtin_amdgcn_s_setprio(1);
#pragma unroll
    for (int ks = 0; ks < 2; ++ks) {
      s8v bp = *(const s8v*)&Pl[wave][lr * 72 + ks * 32 + lg * 8];
#pragma unroll
      for (int mr = 0; mr < 8; ++mr) {
        s8v av = *(const s8v*)&Vt[(mr * 16 + lr) * 72 + ks * 32 + lg * 8];
        cacc[mr] = __builtin_amdgcn_mfma_f32_16x16x32_bf16(av, bp, cacc[mr], 0, 0, 0);
      }
    }
    __builtin_amdgcn_s_setprio(0);
  }
#undef LOADKV
#undef WRITEKV
  float rinv = 1.f / ssum;
#pragma unroll
  for (int mr = 0; mr < 8; ++mr) {
    us4 pk;
#pragma unroll
    for (int j2 = 0; j2 < 4; ++j2) pk[j2] = bf16_rne(cacc[mr][j2] * rinv);
    *(us4*)&CTX[base + (size_t)(q0 + lr) * 128 + mr * 16 + lg * 4] = pk;
  }
}

// ---------------- pregate: CTXG[t][he*128+p] = gate_o[t,he] * ctx[t,h,p] ----------------
__global__ __launch_bounds__(256) void pregate(
    const u16* __restrict__ CTX, const int2* __restrict__ Toi, const float2* __restrict__ Tog,
    u16* __restrict__ CTXG) {
  const int t = blockIdx.x;
  const int tid = threadIdx.x;
  __shared__ float gsh[64];
  if (tid < 64) {
    int h = tid >> 3, e = tid & 7;
    int2 ei = Toi[t * 8 + h];
    float2 gg = Tog[t * 8 + h];
    gsh[tid] = (e == ei.x) ? gg.x : ((e == ei.y) ? gg.y : 0.f);
  }
  __syncthreads();
  const int b = t >> 11, s = t & 2047;
#pragma unroll
  for (int c = 0; c < 4; ++c) {
    int chunk = tid + c * 256;            // 0..1023 chunks of 8 elems
    int he = chunk >> 4, p8 = (chunk & 15) << 3;
    int h = he >> 3;
    float g = gsh[he];
    s8v o;
    if (g != 0.f) {
      s8v v = *(const s8v*)&CTX[((size_t)(b * 8 + h) * 2048 + s) * 128 + p8];
#pragma unroll
      for (int j = 0; j < 8; ++j) o[j] = (short)bf16_rne(bf2f((u16)v[j]) * g);
    } else {
#pragma unroll
      for (int j = 0; j < 8; ++j) o[j] = 0;
    }
    *(s8v*)&CTXG[(size_t)t * 8192 + chunk * 8] = o;
  }
}

// ---------------- O projection: dense 128^2, dbuf prefetch + swizzle, split-K=2 ----------------
// grid (32 tb, 8 db, 2 kz), NATURAL order (R10 XCD remap reverted: 3x FETCH regression).
__global__ __launch_bounds__(256) void gemm_o_dense(
    const u16* __restrict__ CTXG, const u16* __restrict__ Ow /*[d][8192]*/,
    float* __restrict__ OUT, float* __restrict__ OP1a, float* __restrict__ OP1b) {
  __shared__ u16 Ash0[128 * 32], Ash1[128 * 32];
  __shared__ u16 Bsh0[128 * 32], Bsh1[128 * 32];
  const int tb = blockIdx.x, db = blockIdx.y, kz = blockIdx.z;
  const int tid = threadIdx.x;
  const int wave = tid >> 6, lane = tid & 63;
  const int wm = wave >> 1, wn = wave & 1;
  const int lg = lane >> 4, lr = lane & 15;
  const size_t kbase = (size_t)kz * 4096;
  const int r0 = tid >> 2, r1 = (tid + 256) >> 2;
  const int c0 = swzcol(tid), c1 = swzcol(tid + 256);
  const size_t aw0 = (size_t)(tb * 128 + r0) * 8192 + kbase + c0;
  const size_t aw1 = (size_t)(tb * 128 + r1) * 8192 + kbase + c1;
  const size_t bw0 = (size_t)(db * 128 + r0) * 8192 + kbase + c0;
  const size_t bw1 = (size_t)(db * 128 + r1) * 8192 + kbase + c1;
  const int csl = (lg ^ ((lr + (lr >> 2)) & 3)) << 3;
  f4v acc[4][4] = {};
#define STG_O(A, B, k0) do { \
    glds16(&CTXG[aw0 + (k0)], &A[tid * 8]); \
    glds16(&CTXG[aw1 + (k0)], &A[(tid + 256) * 8]); \
    glds16(&Ow[bw0 + (k0)], &B[tid * 8]); \
    glds16(&Ow[bw1 + (k0)], &B[(tid + 256) * 8]); \
  } while (0)
#define CMP_O(A, B) do { \
    s8v af[4], bfr[4]; \
    _Pragma("unroll") for (int m = 0; m < 4; ++m) af[m] = *(const s8v*)&A[(wm * 64 + m * 16 + lr) * 32 + csl]; \
    _Pragma("unroll") for (int n = 0; n < 4; ++n) bfr[n] = *(const s8v*)&B[(wn * 64 + n * 16 + lr) * 32 + csl]; \
    _Pragma("unroll") for (int m = 0; m < 4; ++m) \
      _Pragma("unroll") for (int n = 0; n < 4; ++n) \
        acc[m][n] = __builtin_amdgcn_mfma_f32_16x16x32_bf16(af[m], bfr[n], acc[m][n], 0, 0, 0); \
  } while (0)
  STG_O(Ash0, Bsh0, 0);
  for (int kt = 0; kt < 128; kt += 2) {
    WAITB();
    if (kt + 1 < 128) STG_O(Ash1, Bsh1, (kt + 1) * 32);
    CMP_O(Ash0, Bsh0);
    WAITB();
    if (kt + 2 < 128) STG_O(Ash0, Bsh0, (kt + 2) * 32);
    CMP_O(Ash1, Bsh1);
  }
#undef STG_O
#undef CMP_O
  float* OP;
  if (kz == 0) OP = OUT;
  else OP = (tb < 16) ? OP1a : OP1b;
  const int toff = (kz == 0) ? tb * 128 : (tb & 15) * 128;
#pragma unroll
  for (int m = 0; m < 4; ++m) {
    int t = toff + wm * 64 + m * 16 + lg * 4;
#pragma unroll
    for (int n = 0; n < 4; ++n) {
      int d = db * 128 + wn * 64 + n * 16 + lr;
#pragma unroll
      for (int j2 = 0; j2 < 4; ++j2)
        OP[(size_t)(t + j2) * 1024 + d] = acc[m][n][j2];
    }
  }
}

// ---------------- OUT += partial (split halves) ----------------
__global__ void add_inplace(float* __restrict__ OUT, const float* __restrict__ P0,
                            const float* __restrict__ P1) {
  size_t i = ((size_t)blockIdx.x * 256 + threadIdx.x) * 4;  // 4M floats
  const float* P = (i < 2097152) ? (P0 + i) : (P1 + (i - 2097152));
  float4 a = *(const float4*)&OUT[i];
  float4 b = *(const float4*)P;
  *(float4*)&OUT[i] = make_float4(a.x + b.x, a.y + b.y, a.z + b.z, a.w + b.w);
}

extern "C" void kernel_launch(void* const* d_in, const int* in_sizes, int n_in,
                              void* d_out, int out_size, void* d_ws, size_t ws_size,
                              hipStream_t stream) {
  const float* x     = (const float*)d_in[0];
  const float* q_w   = (const float*)d_in[1];
  const float* k_w   = (const float*)d_in[2];
  const float* v_w   = (const float*)d_in[3];
  const float* o_w   = (const float*)d_in[4];
  const float* sel_v = (const float*)d_in[5];
  const float* sel_o = (const float*)d_in[6];
  const float* rs    = (const float*)d_in[7];

  char* ws = (char*)d_ws;
  const size_t MB = 1048576;
  const size_t KB = 1024;
  // Timeline / overlays (96 MB peak, proven ws >= 97.5 MB):
  u16*    xb    = (u16*)(ws);                        // [0,8M): xb -> ctx -> op1a
  u16*    ctx   = (u16*)(ws);
  float*  op1a  = (float*)(ws);
  u16*    qwb   = (u16*)(ws + 8 * MB);               // [8,10M) dead after gemm_qk
  u16*    kwb   = (u16*)(ws + 10 * MB);              // [10,12M)
  u16*    ctxg  = (u16*)(ws + 8 * MB);               // [8,72M) from pregate on
  u16*    vwT   = (u16*)(ws + 12 * MB);              // [12,28M) dead after gemm_v_e
  u16*    vt    = (u16*)(ws + 12 * MB);              // [12,20M) written after vwT dead
  u16*    vpA   = (u16*)(ws + 28 * MB);              // [28,36M) role-0 partials
  u16*    vpB   = (u16*)(ws + 36 * MB);              // [36,44M) role-1 partials
  u16*    qh    = (u16*)(ws + 49 * MB + 512 * KB);   // [49.5,57.5M)
  u16*    kh    = (u16*)(ws + 57 * MB + 512 * KB);   // [57.5,65.5M)
  int2*   tvi   = (int2*)(ws + 72 * MB);             // [72,80M): routing/bucket meta -> op1b
  float2* tvg   = (float2*)(ws + 72 * MB + 256 * KB);
  int2*   toi   = (int2*)(ws + 72 * MB + 512 * KB);
  float2* tog   = (float2*)(ws + 72 * MB + 768 * KB);
  int*    bcnt2 = (int*)(ws + 73 * MB);              // 256B (pad to 4K)
  u16*    btok2 = (u16*)(ws + 73 * MB + 4 * KB);     // 512K
  float*  bgate2= (float*)(ws + 73 * MB + 520 * KB); // 1M -> ends 73M+1544K
  float*  op1b  = (float*)(ws + 72 * MB);
  u16*    owT   = (u16*)(ws + 80 * MB);              // [80,96M) live until gemm_o_dense
  float*  outp  = (float*)d_out;

  hipLaunchKernelGGL(conv_qk, dim3(2048), dim3(256), 0, stream, q_w, k_w, qwb, kwb);
  hipLaunchKernelGGL(transpose_w, dim3(4, 32, 64), dim3(256), 0, stream, v_w, vwT, 0);
  hipLaunchKernelGGL(transpose_w, dim3(32, 4, 64), dim3(256), 0, stream, o_w, owT, 1);
  hipLaunchKernelGGL(routing, dim3(512), dim3(256), 0, stream, x, sel_v, sel_o, rs, tvi, tvg, toi, tog, xb);
  hipLaunchKernelGGL(build_buckets2, dim3(8), dim3(256), 0, stream, tvi, tvg, bcnt2, btok2, bgate2);
  hipLaunchKernelGGL(gemm_v_e, dim3(32, 64), dim3(256), 0, stream, xb, vwT, bcnt2, btok2, bgate2, vpA, vpB);
  hipLaunchKernelGGL(vadd_transpose, dim3(32, 16), dim3(256), 0, stream, vpA, vpB, vt);
  hipLaunchKernelGGL(gemm_qk, dim3(64, 8, 2), dim3(256), 0, stream, xb, qwb, kwb, qh, kh);
  hipLaunchKernelGGL(attn, dim3(32, 16), dim3(256), 0, stream, qh, kh, vt, ctx);
  hipLaunchKernelGGL(pregate, dim3(4096), dim3(256), 0, stream, ctx, toi, tog, ctxg);
  hipLaunchKernelGGL(gemm_o_dense, dim3(32, 8, 2), dim3(256), 0, stream, ctxg, owT, outp, op1a, op1b);
  hipLaunchKernelGGL(add_inplace, dim3(4096), dim3(256), 0, stream, outp, op1a, op1b);
}

// Round 14
// 366.426 us; speedup vs baseline: 1.7616x; 1.0030x over previous
//
#include <hip/hip_runtime.h>

// SwitchHeadCore: B=2,S=2048,D=1024,H=8,E=8,P=128,K=2(top-k). T = 4096.
// R13: exact revert to R12 (fused-pregate attn had a cross-block WAR race on the
// CTXG overlay; the fusion needs 104MB live > 97.5MB workspace -> infeasible).

typedef unsigned short u16;
typedef __attribute__((ext_vector_type(8))) short s8v;   // 8 x bf16 (MFMA A/B frag)
typedef __attribute__((ext_vector_type(4))) float f4v;   // MFMA C/D frag
typedef __attribute__((ext_vector_type(4))) unsigned short us4;

#define ATT_SCALE 0.08838834764831845f

__device__ inline u16 bf16_rne(float f) {
  union { float f; unsigned u; } v; v.f = f;
  unsigned r = v.u + 0x7fffu + ((v.u >> 16) & 1u);
  return (u16)(r >> 16);
}
__device__ inline float bf2f(u16 h) {
  union { unsigned u; float f; } v; v.u = ((unsigned)h) << 16;
  return v.f;
}

// async global->LDS, 16B per lane. Global src may be per-lane; LDS dest linear in lane order.
__device__ inline void glds16(const void* g, void* l) {
  __builtin_amdgcn_global_load_lds((const __attribute__((address_space(1))) void*)g,
                                   (__attribute__((address_space(3))) void*)l, 16, 0, 0);
}
// swizzled source column (u16 units) for staging lane index idx (rows of 32 u16, 4 slots of 8)
__device__ inline int swzcol(int idx) {
  int r = idx >> 2;
  return (((idx & 3) ^ ((r + (r >> 2)) & 3)) << 3);
}
#define WAITB() do { asm volatile("s_waitcnt vmcnt(0)" ::: "memory"); __syncthreads(); } while (0)

// ---------------- weight prep ----------------
__global__ void conv_qk(const float* __restrict__ Q, const float* __restrict__ K,
                        u16* __restrict__ Qb, u16* __restrict__ Kb) {
  int i = blockIdx.x * 256 + threadIdx.x;
  const float* src; u16* dst; int off;
  if (i < 262144) { src = Q; dst = Qb; off = i; }
  else            { src = K; dst = Kb; off = i - 262144; }
  float4 v = *(const float4*)&src[(size_t)off * 4];
  us4 o; o[0]=bf16_rne(v.x); o[1]=bf16_rne(v.y); o[2]=bf16_rne(v.z); o[3]=bf16_rne(v.w);
  *(us4*)&dst[(size_t)off * 4] = o;
}

// mode 0: v_w [he][1024 d][128 p] -> vwT [h][p][e][d]
// mode 1: o_w [he][128 p][1024 d] -> owT [d][he*128+p]
__global__ void transpose_w(const float* __restrict__ src, u16* __restrict__ dst, int mode) {
  __shared__ float tile[32][33];
  int he = blockIdx.z;
  int C = mode ? 1024 : 128;
  int r0 = blockIdx.y * 32, c0 = blockIdx.x * 32;
  int lc = threadIdx.x & 31, rr = threadIdx.x >> 5;
  const float* s = src + (size_t)he * 131072;
#pragma unroll
  for (int i = 0; i < 4; ++i) {
    int r = rr + i * 8;
    tile[r][lc] = s[(size_t)(r0 + r) * C + c0 + lc];
  }
  __syncthreads();
#pragma unroll
  for (int i = 0; i < 4; ++i) {
    int c = rr + i * 8;
    float v = tile[lc][c];
    size_t a;
    if (mode) a = (size_t)(c0 + c) * 8192 + (size_t)he * 128 + (r0 + lc);
    else      a = (size_t)(he >> 3) * 1048576 + (size_t)(c0 + c) * 8192 + (size_t)(he & 7) * 1024 + (r0 + lc);
    dst[a] = bf16_rne(v);
  }
}

// ---------------- routing + x->bf16 ----------------
__global__ __launch_bounds__(256, 2) void routing(
    const float* __restrict__ X, const float* __restrict__ SelV, const float* __restrict__ SelO,
    const float* __restrict__ RS, int2* __restrict__ Tvi, float2* __restrict__ Tvg,
    int2* __restrict__ Toi, float2* __restrict__ Tog, u16* __restrict__ Xb) {
  __shared__ float xs[8][1024];
  __shared__ float lgs[8][128];
  int t0 = blockIdx.x * 8;
  int tid = threadIdx.x;
  for (int i = tid; i < 2048; i += 256) {
    int row = i >> 8, c = (i & 255) * 4;
    float4 v = *(const float4*)&X[(size_t)(t0 + row) * 1024 + c];
    *(float4*)&xs[row][c] = v;
    us4 o; o[0]=bf16_rne(v.x); o[1]=bf16_rne(v.y); o[2]=bf16_rne(v.z); o[3]=bf16_rne(v.w);
    *(us4*)&Xb[(size_t)(t0 + row) * 1024 + c] = o;
  }
  __syncthreads();
  {
    int widx = tid & 127, tg = tid >> 7;
    const float* w = (widx < 64) ? (SelV + (size_t)widx * 1024) : (SelO + (size_t)(widx - 64) * 1024);
    float acc[4] = {0.f, 0.f, 0.f, 0.f};
    for (int k = 0; k < 1024; k += 4) {
      float4 wv = *(const float4*)&w[k];
#pragma unroll
      for (int t = 0; t < 4; ++t) {
        float4 xv = *(const float4*)&xs[tg * 4 + t][k];
        acc[t] += wv.x * xv.x + wv.y * xv.y + wv.z * xv.z + wv.w * xv.w;
      }
    }
#pragma unroll
    for (int t = 0; t < 4; ++t) lgs[tg * 4 + t][widx] = acc[t];
  }
  __syncthreads();
  if (tid < 128) {
    float rs = RS[0];
    int tok = tid >> 4, which = (tid >> 3) & 1, h = tid & 7;
    float p[8];
#pragma unroll
    for (int e = 0; e < 8; ++e)
      p[e] = 1.f / (1.f + __expf(-lgs[tok][which * 64 + h * 8 + e]));
    float v1 = -1.f; int i1 = -1;
#pragma unroll
    for (int e = 0; e < 8; ++e) if (p[e] > v1) { v1 = p[e]; i1 = e; }
    float v2 = -1.f; int i2 = -1;
#pragma unroll
    for (int e = 0; e < 8; ++e) if (e != i1 && p[e] > v2) { v2 = p[e]; i2 = e; }
    float ssum = fmaxf(v1 + v2, 1e-9f);
    float g1 = v1 / ssum * rs, g2 = v2 / ssum * rs;
    int t = t0 + tok;
    int lo, hi; float glo, ghi;
    if (i1 < i2) { lo = i1; hi = i2; glo = g1; ghi = g2; }
    else         { lo = i2; hi = i1; glo = g2; ghi = g1; }
    if (which) { Toi[t * 8 + h] = make_int2(lo, hi); Tog[t * 8 + h] = make_float2(glo, ghi); }
    else       { Tvi[t * 8 + h] = make_int2(lo, hi); Tvg[t * 8 + h] = make_float2(glo, ghi); }
  }
}

// ---------------- V bucket build v3: wave-aggregated, LDS counters, 1 block/head ----------------
__global__ __launch_bounds__(256) void build_buckets2(
    const int2* __restrict__ Tvi, const float2* __restrict__ Tvg,
    int* __restrict__ bcnt, u16* __restrict__ btok, float* __restrict__ bgate) {
  const int h = blockIdx.x;
  const int tid = threadIdx.x;
  const int lane = tid & 63;
  __shared__ int cnt[8];
  if (tid < 8) cnt[tid] = 0;
  __syncthreads();
  for (int chunk = 0; chunk < 16; ++chunk) {
    int t = chunk * 256 + tid;
    int2 e = Tvi[t * 8 + h];
    float2 g = Tvg[t * 8 + h];
#pragma unroll
    for (int role = 0; role < 2; ++role) {
      int mye = role ? e.y : e.x;
      float myg = role ? g.y : g.x;
      u16 entry = role ? (u16)(t | 0x8000) : (u16)t;
#pragma unroll
      for (int ee = 0; ee < 8; ++ee) {
        unsigned long long mask = __ballot(mye == ee);
        if (mye == ee) {
          int prefix = __popcll(mask & ((1ull << lane) - 1ull));
          int leader = __ffsll((unsigned long long)mask) - 1;
          int base = 0;
          if (lane == leader) base = atomicAdd(&cnt[ee], (int)__popcll(mask));
          base = __shfl(base, leader);
          int pos = base + prefix;
          btok[(h * 8 + ee) * 4096 + pos] = entry;
          bgate[(h * 8 + ee) * 4096 + pos] = myg;
        }
      }
    }
  }
  __syncthreads();
  if (tid < 8) bcnt[h * 8 + tid] = cnt[tid];
}

// ---------------- Q/K projection GEMM: 64x128 tile, dbuf prefetch + swizzle ----------------
// grid (64 tb, 8 nb, 2 qk)
__global__ __launch_bounds__(256) void gemm_qk(
    const u16* __restrict__ Xb, const u16* __restrict__ Wq, const u16* __restrict__ Wk,
    u16* __restrict__ Qo, u16* __restrict__ Ko) {
  __shared__ u16 Ash0[64 * 32], Ash1[64 * 32];
  __shared__ u16 Bsh0[128 * 32], Bsh1[128 * 32];
  const int tb = blockIdx.x, nb = blockIdx.y;
  const u16* W = blockIdx.z ? Wk : Wq;
  u16* Out = blockIdx.z ? Ko : Qo;
  const int tid = threadIdx.x;
  const int wave = tid >> 6, lane = tid & 63;
  const int lg = lane >> 4, lr = lane & 15;
  const int r0 = tid >> 2, r1 = (tid + 256) >> 2;
  const int c0 = swzcol(tid), c1 = swzcol(tid + 256);
  const size_t aw  = (size_t)(tb * 64 + r0) * 1024 + c0;
  const size_t bw0 = (size_t)(nb * 128 + r0) * 1024 + c0;
  const size_t bw1 = (size_t)(nb * 128 + r1) * 1024 + c1;
  const int csl = (lg ^ ((lr + (lr >> 2)) & 3)) << 3;
  f4v acc[4][2] = {};
#define STG_QK(A, B, k0) do { \
    glds16(&Xb[aw + (k0)], &A[tid * 8]); \
    glds16(&W[bw0 + (k0)], &B[tid * 8]); \
    glds16(&W[bw1 + (k0)], &B[(tid + 256) * 8]); \
  } while (0)
#define CMP_QK(A, B) do { \
    s8v af[4], bfr[2]; \
    _Pragma("unroll") for (int m = 0; m < 4; ++m) af[m] = *(const s8v*)&A[(m * 16 + lr) * 32 + csl]; \
    _Pragma("unroll") for (int n = 0; n < 2; ++n) bfr[n] = *(const s8v*)&B[(wave * 32 + n * 16 + lr) * 32 + csl]; \
    _Pragma("unroll") for (int m = 0; m < 4; ++m) \
      _Pragma("unroll") for (int n = 0; n < 2; ++n) \
        acc[m][n] = __builtin_amdgcn_mfma_f32_16x16x32_bf16(af[m], bfr[n], acc[m][n], 0, 0, 0); \
  } while (0)
  STG_QK(Ash0, Bsh0, 0);
  for (int kt = 0; kt < 32; kt += 2) {
    WAITB();
    if (kt + 1 < 32) STG_QK(Ash1, Bsh1, (kt + 1) * 32);
    CMP_QK(Ash0, Bsh0);
    WAITB();
    if (kt + 2 < 32) STG_QK(Ash0, Bsh0, (kt + 2) * 32);
    CMP_QK(Ash1, Bsh1);
  }
#undef STG_QK
#undef CMP_QK
#pragma unroll
  for (int m = 0; m < 4; ++m) {
    int tbase = tb * 64 + m * 16 + lg * 4;
    int b = tbase >> 11, s = tbase & 2047;
#pragma unroll
    for (int n = 0; n < 2; ++n) {
      int p = wave * 32 + n * 16 + lr;
      size_t base = ((size_t)(b * 8 + nb) * 2048 + s) * 128 + p;
#pragma unroll
      for (int j = 0; j < 4; ++j)
        Out[base + (size_t)j * 128] = bf16_rne(acc[m][n][j]);
    }
  }
}

// ---------------- V expert GEMM v3: per-(h,e) buckets, 128x128 tile, role-split partials ----------------
// grid (32 tiles, 64 buckets) with XCD-aware remap: XCD k owns buckets 8k..8k+7 (B panels L2-resident).
__global__ __launch_bounds__(256) void gemm_v_e(
    const u16* __restrict__ Xb, const u16* __restrict__ Vw /*[h][p][e][d]*/,
    const int* __restrict__ bcnt, const u16* __restrict__ btok,
    const float* __restrict__ bgate, u16* __restrict__ VpA, u16* __restrict__ VpB) {
  const int id = blockIdx.x + 32 * blockIdx.y;
  const int xk = id & 7, j = id >> 3;          // j in 0..255
  const int bucket = 8 * xk + (j & 7);
  const int tile = j >> 3;                     // 0..31
  const int h = bucket >> 3, e = bucket & 7;
  const int cnt = bcnt[bucket];
  if (tile * 128 >= cnt) return;
  __shared__ u16 Ash0[128 * 32], Ash1[128 * 32];
  __shared__ u16 Bsh0[128 * 32], Bsh1[128 * 32];
  __shared__ int toksh[128];
  __shared__ float gsh[128];
  const int tid = threadIdx.x;
  if (tid < 128) {
    int ar = tile * 128 + tid;
    if (ar < cnt) {
      toksh[tid] = btok[bucket * 4096 + ar];
      gsh[tid] = bgate[bucket * 4096 + ar];
    } else { toksh[tid] = 0; gsh[tid] = 0.f; }
  }
  __syncthreads();
  const int wave = tid >> 6, lane = tid & 63;
  const int wm = wave >> 1, wn = wave & 1;
  const int lg = lane >> 4, lr = lane & 15;
  const int r0 = tid >> 2, r1 = (tid + 256) >> 2;
  const int c0 = swzcol(tid), c1 = swzcol(tid + 256);
  const size_t aw0 = (size_t)(toksh[r0] & 0xFFF) * 1024 + c0;
  const size_t aw1 = (size_t)(toksh[r1] & 0xFFF) * 1024 + c1;
  const size_t bw0 = ((size_t)(h * 128 + r0) * 8 + e) * 1024 + c0;
  const size_t bw1 = ((size_t)(h * 128 + r1) * 8 + e) * 1024 + c1;
  const int csl = (lg ^ ((lr + (lr >> 2)) & 3)) << 3;
  f4v acc[4][4] = {};
#define STG_VE(A, B, k0) do { \
    glds16(&Xb[aw0 + (k0)], &A[tid * 8]); \
    glds16(&Xb[aw1 + (k0)], &A[(tid + 256) * 8]); \
    glds16(&Vw[bw0 + (k0)], &B[tid * 8]); \
    glds16(&Vw[bw1 + (k0)], &B[(tid + 256) * 8]); \
  } while (0)
#define CMP_VE(A, B) do { \
    s8v af[4], bfr[4]; \
    _Pragma("unroll") for (int m = 0; m < 4; ++m) af[m] = *(const s8v*)&A[(wm * 64 + m * 16 + lr) * 32 + csl]; \
    _Pragma("unroll") for (int n = 0; n < 4; ++n) bfr[n] = *(const s8v*)&B[(wn * 64 + n * 16 + lr) * 32 + csl]; \
    _Pragma("unroll") for (int m = 0; m < 4; ++m) \
      _Pragma("unroll") for (int n = 0; n < 4; ++n) \
        acc[m][n] = __builtin_amdgcn_mfma_f32_16x16x32_bf16(af[m], bfr[n], acc[m][n], 0, 0, 0); \
  } while (0)
  STG_VE(Ash0, Bsh0, 0);
  for (int kt = 0; kt < 32; kt += 2) {
    WAITB();
    if (kt + 1 < 32) STG_VE(Ash1, Bsh1, (kt + 1) * 32);
    CMP_VE(Ash0, Bsh0);
    WAITB();
    if (kt + 2 < 32) STG_VE(Ash0, Bsh0, (kt + 2) * 32);
    CMP_VE(Ash1, Bsh1);
  }
#undef STG_VE
#undef CMP_VE
#pragma unroll
  for (int m = 0; m < 4; ++m) {
#pragma unroll
    for (int j2 = 0; j2 < 4; ++j2) {
      int row = wm * 64 + m * 16 + lg * 4 + j2;
      int ar = tile * 128 + row;
      if (ar < cnt) {
        int entry = toksh[row];
        int tok = entry & 0xFFF;
        u16* dst = (entry & 0x8000) ? VpB : VpA;
        float g = gsh[row];
#pragma unroll
        for (int n = 0; n < 4; ++n) {
          int p = wn * 64 + n * 16 + lr;
          dst[(size_t)tok * 1024 + h * 128 + p] = bf16_rne(g * acc[m][n][j2]);
        }
      }
    }
  }
}

// ---------------- vadd_transpose: VT[bh][p][s] = VpA[t][hp] + VpB[t][hp] ----------------
__global__ void vadd_transpose(const u16* __restrict__ VpA, const u16* __restrict__ VpB,
                               u16* __restrict__ VT) {
  __shared__ u16 tile[64][136];
  const int sb = blockIdx.x, bh = blockIdx.y;
  const int b = bh >> 3, h = bh & 7;
  const int tid = threadIdx.x;
#pragma unroll
  for (int it = 0; it < 4; ++it) {
    int idx = tid + it * 256;
    int r = idx >> 4, c8 = (idx & 15) << 3;
    size_t off = (size_t)(b * 2048 + sb * 64 + r) * 1024 + h * 128 + c8;
    s8v va = *(const s8v*)&VpA[off];
    s8v vb = *(const s8v*)&VpB[off];
    s8v o;
#pragma unroll
    for (int j = 0; j < 8; ++j) o[j] = (short)bf16_rne(bf2f((u16)va[j]) + bf2f((u16)vb[j]));
    *(s8v*)&tile[r][c8] = o;
  }
  __syncthreads();
#pragma unroll
  for (int it = 0; it < 8; ++it) {
    int idx = tid + it * 256;
    int p = idx >> 4, c4 = (idx & 15) << 2;
    us4 o;
#pragma unroll
    for (int j = 0; j < 4; ++j) o[j] = tile[c4 + j][p];
    *(us4*)&VT[((size_t)bh * 128 + p) * 2048 + sb * 64 + c4] = o;
  }
}

// ---------------- attention: XCD remap + setprio + async-stage (load-early / write-late) ----------------
// 512 blocks: XCD k owns bh {2k, 2k+1}. K/V for tile kb+1 loaded to regs during compute of tile kb.
__global__ __launch_bounds__(256, 2) void attn(
    const u16* __restrict__ Q, const u16* __restrict__ K,
    const u16* __restrict__ VT, u16* __restrict__ CTX) {
  __shared__ u16 Kt[64 * 136];
  __shared__ u16 Vt[128 * 72];
  __shared__ u16 Pl[4][16 * 72];
  const int id = blockIdx.x + 32 * blockIdx.y;
  const int xk = id & 7, j = id >> 3;          // j in 0..63
  const int bh = 2 * xk + (j >> 5);
  const int qb = j & 31;
  const int tid = threadIdx.x;
  const int wave = tid >> 6, lane = tid & 63;
  const int lg = lane >> 4, lr = lane & 15;
  const size_t base = (size_t)bh * 2048 * 128;
  const int q0 = qb * 64 + wave * 16;
  s8v qf[4];
#pragma unroll
  for (int ks = 0; ks < 4; ++ks)
    qf[ks] = *(const s8v*)&Q[base + (size_t)(q0 + lr) * 128 + ks * 32 + lg * 8];
  s8v kr[4], vr[4];
#define LOADKV(kb) do { \
    _Pragma("unroll") for (int i = 0; i < 4; ++i) { \
      int idx = tid + i * 256; \
      kr[i] = *(const s8v*)&K[base + (size_t)((kb) * 64 + (idx >> 4)) * 128 + ((idx & 15) << 3)]; \
      vr[i] = *(const s8v*)&VT[base + (size_t)(idx >> 3) * 2048 + (kb) * 64 + ((idx & 7) << 3)]; \
    } } while (0)
#define WRITEKV() do { \
    _Pragma("unroll") for (int i = 0; i < 4; ++i) { \
      int idx = tid + i * 256; \
      *(s8v*)&Kt[(idx >> 4) * 136 + ((idx & 15) << 3)] = kr[i]; \
      *(s8v*)&Vt[(idx >> 3) * 72 + ((idx & 7) << 3)] = vr[i]; \
    } } while (0)
  f4v cacc[8] = {};
  float mrun = -1e30f, ssum = 0.f;
  LOADKV(0);
  for (int kb = 0; kb < 32; ++kb) {
    asm volatile("s_waitcnt vmcnt(0)" ::: "memory");  // next-tile regs valid
    __syncthreads();                                   // all waves done with LDS
    WRITEKV();
    __syncthreads();                                   // LDS tile visible
    if (kb + 1 < 32) LOADKV(kb + 1);                   // HBM latency hides under compute below
    f4v sc[4] = {};
    __builtin_amdgcn_s_setprio(1);
#pragma unroll
    for (int ks = 0; ks < 4; ++ks) {
#pragma unroll
      for (int m = 0; m < 4; ++m) {
        s8v ak = *(const s8v*)&Kt[(m * 16 + lr) * 136 + ks * 32 + lg * 8];
        sc[m] = __builtin_amdgcn_mfma_f32_16x16x32_bf16(ak, qf[ks], sc[m], 0, 0, 0);
      }
    }
    __builtin_amdgcn_s_setprio(0);
    float tmax = -1e30f;
#pragma unroll
    for (int m = 0; m < 4; ++m)
#pragma unroll
      for (int j2 = 0; j2 < 4; ++j2) {
        float v = sc[m][j2] * ATT_SCALE;
        sc[m][j2] = v;
        tmax = fmaxf(tmax, v);
      }
    tmax = fmaxf(tmax, __shfl_xor(tmax, 16));
    tmax = fmaxf(tmax, __shfl_xor(tmax, 32));
    float mnew = fmaxf(mrun, tmax);
    float f = __expf(mrun - mnew);
    mrun = mnew;
    float psum = 0.f;
#pragma unroll
    for (int m = 0; m < 4; ++m) {
      us4 pk;
#pragma unroll
      for (int j2 = 0; j2 < 4; ++j2) {
        float pe = __expf(sc[m][j2] - mnew);
        psum += pe;
        pk[j2] = bf16_rne(pe);
      }
      *(us4*)&Pl[wave][lr * 72 + m * 16 + lg * 4] = pk;
    }
    psum += __shfl_xor(psum, 16);
    psum += __shfl_xor(psum, 32);
    ssum = ssum * f + psum;
#pragma unroll
    for (int mr = 0; mr < 8; ++mr)
#pragma unroll
      for (int j2 = 0; j2 < 4; ++j2) cacc[mr][j2] *= f;
    __builtin_amdgcn_s_setprio(1);
#pragma unroll
    for (int ks = 0; ks < 2; ++ks) {
      s8v bp = *(const s8v*)&Pl[wave][lr * 72 + ks * 32 + lg * 8];
#pragma unroll
      for (int mr = 0; mr < 8; ++mr) {
        s8v av = *(const s8v*)&Vt[(mr * 16 + lr) * 72 + ks * 32 + lg * 8];
        cacc[mr] = __builtin_amdgcn_mfma_f32_16x16x32_bf16(av, bp, cacc[mr], 0, 0, 0);
      }
    }
    __builtin_amdgcn_s_setprio(0);
  }
#undef LOADKV
#undef WRITEKV
  float rinv = 1.f / ssum;
#pragma unroll
  for (int mr = 0; mr < 8; ++mr) {
    us4 pk;
#pragma unroll
    for (int j2 = 0; j2 < 4; ++j2) pk[j2] = bf16_rne(cacc[mr][j2] * rinv);
    *(us4*)&CTX[base + (size_t)(q0 + lr) * 128 + mr * 16 + lg * 4] = pk;
  }
}

// ---------------- pregate: CTXG[t][he*128+p] = gate_o[t,he] * ctx[t,h,p] ----------------
__global__ __launch_bounds__(256) void pregate(
    const u16* __restrict__ CTX, const int2* __restrict__ Toi, const float2* __restrict__ Tog,
    u16* __restrict__ CTXG) {
  const int t = blockIdx.x;
  const int tid = threadIdx.x;
  __shared__ float gsh[64];
  if (tid < 64) {
    int h = tid >> 3, e = tid & 7;
    int2 ei = Toi[t * 8 + h];
    float2 gg = Tog[t * 8 + h];
    gsh[tid] = (e == ei.x) ? gg.x : ((e == ei.y) ? gg.y : 0.f);
  }
  __syncthreads();
  const int b = t >> 11, s = t & 2047;
#pragma unroll
  for (int c = 0; c < 4; ++c) {
    int chunk = tid + c * 256;            // 0..1023 chunks of 8 elems
    int he = chunk >> 4, p8 = (chunk & 15) << 3;
    int h = he >> 3;
    float g = gsh[he];
    s8v o;
    if (g != 0.f) {
      s8v v = *(const s8v*)&CTX[((size_t)(b * 8 + h) * 2048 + s) * 128 + p8];
#pragma unroll
      for (int j = 0; j < 8; ++j) o[j] = (short)bf16_rne(bf2f((u16)v[j]) * g);
    } else {
#pragma unroll
      for (int j = 0; j < 8; ++j) o[j] = 0;
    }
    *(s8v*)&CTXG[(size_t)t * 8192 + chunk * 8] = o;
  }
}

// ---------------- O projection: dense 128^2, dbuf prefetch + swizzle, split-K=2 ----------------
// grid (32 tb, 8 db, 2 kz), NATURAL order (R10 XCD remap reverted: 3x FETCH regression).
__global__ __launch_bounds__(256) void gemm_o_dense(
    const u16* __restrict__ CTXG, const u16* __restrict__ Ow /*[d][8192]*/,
    float* __restrict__ OUT, float* __restrict__ OP1a, float* __restrict__ OP1b) {
  __shared__ u16 Ash0[128 * 32], Ash1[128 * 32];
  __shared__ u16 Bsh0[128 * 32], Bsh1[128 * 32];
  const int tb = blockIdx.x, db = blockIdx.y, kz = blockIdx.z;
  const int tid = threadIdx.x;
  const int wave = tid >> 6, lane = tid & 63;
  const int wm = wave >> 1, wn = wave & 1;
  const int lg = lane >> 4, lr = lane & 15;
  const size_t kbase = (size_t)kz * 4096;
  const int r0 = tid >> 2, r1 = (tid + 256) >> 2;
  const int c0 = swzcol(tid), c1 = swzcol(tid + 256);
  const size_t aw0 = (size_t)(tb * 128 + r0) * 8192 + kbase + c0;
  const size_t aw1 = (size_t)(tb * 128 + r1) * 8192 + kbase + c1;
  const size_t bw0 = (size_t)(db * 128 + r0) * 8192 + kbase + c0;
  const size_t bw1 = (size_t)(db * 128 + r1) * 8192 + kbase + c1;
  const int csl = (lg ^ ((lr + (lr >> 2)) & 3)) << 3;
  f4v acc[4][4] = {};
#define STG_O(A, B, k0) do { \
    glds16(&CTXG[aw0 + (k0)], &A[tid * 8]); \
    glds16(&CTXG[aw1 + (k0)], &A[(tid + 256) * 8]); \
    glds16(&Ow[bw0 + (k0)], &B[tid * 8]); \
    glds16(&Ow[bw1 + (k0)], &B[(tid + 256) * 8]); \
  } while (0)
#define CMP_O(A, B) do { \
    s8v af[4], bfr[4]; \
    _Pragma("unroll") for (int m = 0; m < 4; ++m) af[m] = *(const s8v*)&A[(wm * 64 + m * 16 + lr) * 32 + csl]; \
    _Pragma("unroll") for (int n = 0; n < 4; ++n) bfr[n] = *(const s8v*)&B[(wn * 64 + n * 16 + lr) * 32 + csl]; \
    _Pragma("unroll") for (int m = 0; m < 4; ++m) \
      _Pragma("unroll") for (int n = 0; n < 4; ++n) \
        acc[m][n] = __builtin_amdgcn_mfma_f32_16x16x32_bf16(af[m], bfr[n], acc[m][n], 0, 0, 0); \
  } while (0)
  STG_O(Ash0, Bsh0, 0);
  for (int kt = 0; kt < 128; kt += 2) {
    WAITB();
    if (kt + 1 < 128) STG_O(Ash1, Bsh1, (kt + 1) * 32);
    CMP_O(Ash0, Bsh0);
    WAITB();
    if (kt + 2 < 128) STG_O(Ash0, Bsh0, (kt + 2) * 32);
    CMP_O(Ash1, Bsh1);
  }
#undef STG_O
#undef CMP_O
  float* OP;
  if (kz == 0) OP = OUT;
  else OP = (tb < 16) ? OP1a : OP1b;
  const int toff = (kz == 0) ? tb * 128 : (tb & 15) * 128;
#pragma unroll
  for (int m = 0; m < 4; ++m) {
    int t = toff + wm * 64 + m * 16 + lg * 4;
#pragma unroll
    for (int n = 0; n < 4; ++n) {
      int d = db * 128 + wn * 64 + n * 16 + lr;
#pragma unroll
      for (int j2 = 0; j2 < 4; ++j2)
        OP[(size_t)(t + j2) * 1024 + d] = acc[m][n][j2];
    }
  }
}

// ---------------- OUT += partial (split halves) ----------------
__global__ void add_inplace(float* __restrict__ OUT, const float* __restrict__ P0,
                            const float* __restrict__ P1) {
  size_t i = ((size_t)blockIdx.x * 256 + threadIdx.x) * 4;  // 4M floats
  const float* P = (i < 2097152) ? (P0 + i) : (P1 + (i - 2097152));
  float4 a = *(const float4*)&OUT[i];
  float4 b = *(const float4*)P;
  *(float4*)&OUT[i] = make_float4(a.x + b.x, a.y + b.y, a.z + b.z, a.w + b.w);
}

extern "C" void kernel_launch(void* const* d_in, const int* in_sizes, int n_in,
                              void* d_out, int out_size, void* d_ws, size_t ws_size,
                              hipStream_t stream) {
  const float* x     = (const float*)d_in[0];
  const float* q_w   = (const float*)d_in[1];
  const float* k_w   = (const float*)d_in[2];
  const float* v_w   = (const float*)d_in[3];
  const float* o_w   = (const float*)d_in[4];
  const float* sel_v = (const float*)d_in[5];
  const float* sel_o = (const float*)d_in[6];
  const float* rs    = (const float*)d_in[7];

  char* ws = (char*)d_ws;
  const size_t MB = 1048576;
  const size_t KB = 1024;
  // Timeline / overlays (96 MB peak, proven ws >= 97.5 MB):
  u16*    xb    = (u16*)(ws);                        // [0,8M): xb -> ctx -> op1a
  u16*    ctx   = (u16*)(ws);
  float*  op1a  = (float*)(ws);
  u16*    qwb   = (u16*)(ws + 8 * MB);               // [8,10M) dead after gemm_qk
  u16*    kwb   = (u16*)(ws + 10 * MB);              // [10,12M)
  u16*    ctxg  = (u16*)(ws + 8 * MB);               // [8,72M) from pregate on
  u16*    vwT   = (u16*)(ws + 12 * MB);              // [12,28M) dead after gemm_v_e
  u16*    vt    = (u16*)(ws + 12 * MB);              // [12,20M) written after vwT dead
  u16*    vpA   = (u16*)(ws + 28 * MB);              // [28,36M) role-0 partials
  u16*    vpB   = (u16*)(ws + 36 * MB);              // [36,44M) role-1 partials
  u16*    qh    = (u16*)(ws + 49 * MB + 512 * KB);   // [49.5,57.5M)
  u16*    kh    = (u16*)(ws + 57 * MB + 512 * KB);   // [57.5,65.5M)
  int2*   tvi   = (int2*)(ws + 72 * MB);             // [72,80M): routing/bucket meta -> op1b
  float2* tvg   = (float2*)(ws + 72 * MB + 256 * KB);
  int2*   toi   = (int2*)(ws + 72 * MB + 512 * KB);
  float2* tog   = (float2*)(ws + 72 * MB + 768 * KB);
  int*    bcnt2 = (int*)(ws + 73 * MB);              // 256B (pad to 4K)
  u16*    btok2 = (u16*)(ws + 73 * MB + 4 * KB);     // 512K
  float*  bgate2= (float*)(ws + 73 * MB + 520 * KB); // 1M -> ends 73M+1544K
  float*  op1b  = (float*)(ws + 72 * MB);
  u16*    owT   = (u16*)(ws + 80 * MB);              // [80,96M) live until gemm_o_dense
  float*  outp  = (float*)d_out;

  hipLaunchKernelGGL(conv_qk, dim3(2048), dim3(256), 0, stream, q_w, k_w, qwb, kwb);
  hipLaunchKernelGGL(transpose_w, dim3(4, 32, 64), dim3(256), 0, stream, v_w, vwT, 0);
  hipLaunchKernelGGL(transpose_w, dim3(32, 4, 64), dim3(256), 0, stream, o_w, owT, 1);
  hipLaunchKernelGGL(routing, dim3(512), dim3(256), 0, stream, x, sel_v, sel_o, rs, tvi, tvg, toi, tog, xb);
  hipLaunchKernelGGL(build_buckets2, dim3(8), dim3(256), 0, stream, tvi, tvg, bcnt2, btok2, bgate2);
  hipLaunchKernelGGL(gemm_v_e, dim3(32, 64), dim3(256), 0, stream, xb, vwT, bcnt2, btok2, bgate2, vpA, vpB);
  hipLaunchKernelGGL(vadd_transpose, dim3(32, 16), dim3(256), 0, stream, vpA, vpB, vt);
  hipLaunchKernelGGL(gemm_qk, dim3(64, 8, 2), dim3(256), 0, stream, xb, qwb, kwb, qh, kh);
  hipLaunchKernelGGL(attn, dim3(32, 16), dim3(256), 0, stream, qh, kh, vt, ctx);
  hipLaunchKernelGGL(pregate, dim3(4096), dim3(256), 0, stream, ctx, toi, tog, ctxg);
  hipLaunchKernelGGL(gemm_o_dense, dim3(32, 8, 2), dim3(256), 0, stream, ctxg, owT, outp, op1a, op1b);
  hipLaunchKernelGGL(add_inplace, dim3(4096), dim3(256), 0, stream, outp, op1a, op1b);
}